// Round 7
// baseline (293.307 us; speedup 1.0000x reference)
//
#include <hip/hip_runtime.h>
#include <hip/hip_bf16.h>

// ===== Problem constants =====
// B=8, N=1025, C=768, H=12, HD=64
constexpr int NTOK   = 1025;
constexpr int M      = 8 * NTOK;      // 8200 tokens
constexpr int MP     = 8320;          // 65 * 128 padded rows
constexpr int KDIM   = 768;
constexpr int NQKV   = 2304;
constexpr int NKVPAD = 1088;          // 17*64 padded kv length for vT
constexpr float SCALEL2 = 0.125f * 1.44269504f; // 64^-0.5 * log2(e), folded into K

using bf16x8 = __attribute__((ext_vector_type(8))) short;
using f32x4  = __attribute__((ext_vector_type(4))) float;

__device__ __forceinline__ f32x4 mfma_bf16(bf16x8 a, bf16x8 b, f32x4 c) {
  return __builtin_amdgcn_mfma_f32_16x16x32_bf16(a, b, c, 0, 0, 0);
}

__device__ __forceinline__ void gl16(const void* g, void* l) {
  __builtin_amdgcn_global_load_lds(
      (const __attribute__((address_space(1))) void*)g,
      (__attribute__((address_space(3))) void*)l, 16, 0, 0);
}

// ===== Workspace layout (bytes), all 256-aligned =====
constexpr size_t SZ_X     = (size_t)MP * KDIM * 2;        // 12,779,520
constexpr size_t SZ_WQ    = (size_t)NQKV * KDIM * 2;      // 3,538,944
constexpr size_t SZ_PW    = (size_t)KDIM * KDIM * 2;      // 1,179,648
constexpr size_t SZ_QK    = (size_t)96 * NTOK * 64 * 2;   // 12,595,200
constexpr size_t SZ_VT    = (size_t)96 * 64 * NKVPAD * 2; // 13,369,344
constexpr size_t OFF_XHI  = 0;
constexpr size_t OFF_XLO  = OFF_XHI + SZ_X;
constexpr size_t OFF_WQHI = OFF_XLO + SZ_X;
constexpr size_t OFF_PWHI = OFF_WQHI + SZ_WQ;
constexpr size_t OFF_PWLO = OFF_PWHI + SZ_PW;
constexpr size_t OFF_Q    = OFF_PWLO + SZ_PW;
constexpr size_t OFF_K    = OFF_Q + SZ_QK;
constexpr size_t OFF_VT   = OFF_K + SZ_QK;
constexpr size_t OFF_AO   = OFF_VT + SZ_VT;
// total ~83 MB

// ===== K0a: fp32 -> (hi,lo) bf16 split, zero tail =====
__global__ void k_split(const float* __restrict__ src, __hip_bfloat16* __restrict__ hi,
                        __hip_bfloat16* __restrict__ lo, int n_src, int n_dst) {
  int i = blockIdx.x * 256 + threadIdx.x;
  if (i >= n_dst) return;
  float v = (i < n_src) ? src[i] : 0.0f;
  __hip_bfloat16 h = __float2bfloat16(v);
  hi[i] = h;
  lo[i] = __float2bfloat16(v - __bfloat162float(h));
}

// K0b: fp32 -> bf16 (hi only)
__global__ void k_tobf16(const float* __restrict__ src, __hip_bfloat16* __restrict__ dst,
                         int n) {
  int i = blockIdx.x * 256 + threadIdx.x;
  if (i >= n) return;
  dst[i] = __float2bfloat16(src[i]);
}

// zero vT pad columns (keys 1025..1087) so PV MFMA never sees NaN garbage
__global__ void k_zero_vt(__hip_bfloat16* __restrict__ vt) {
  int i = blockIdx.x * 256 + threadIdx.x;
  constexpr int NPADC = NKVPAD - NTOK; // 63
  if (i >= 96 * 64 * NPADC) return;
  int r = i / NPADC;
  int c = NTOK + (i - r * NPADC);
  vt[(size_t)r * NKVPAD + c] = __float2bfloat16(0.0f);
}

// ===== GEMM core: 128x128 tile, BK=32, 2-term split, swizzled LDS =====
// 2-phase double-buffered staging: stage(t+1) is issued BEFORE compute(t);
// the single __syncthreads per step drains only the latency tail that the
// 32 MFMAs + 12 ds_read_b128 didn't already cover (T3 minimal recipe).
// SPLIT_A=1: acc = Ah*Bh + Al*Bh   (Asec = A_lo, row base mBase)
// SPLIT_A=0: acc = Ah*Bh + Ah*Bl   (Asec = B_lo, row base nBase)
// LDS swizzle (conflict-free ds_read_b128 with linear global_load_lds dest):
//   chunk c (16B) holds global (row=c>>2, slot=(c&3)^((row>>1)&3)) of the tile;
//   4-lane groups still fetch the same contiguous 64B from global (coalesced).
// EPI=0: QKV -> bias + RoPE -> q,k ([bh][t][d] bf16; K pre-scaled by SCALEL2)
//        and vT ([bh][d][t_pad] bf16)
// EPI=1: proj -> bias -> fp32 d_out
template <int EPI, bool SPLIT_A>
__global__ __launch_bounds__(256) void k_gemm(
    const __hip_bfloat16* __restrict__ Ahi, const __hip_bfloat16* __restrict__ Asec,
    const __hip_bfloat16* __restrict__ Bhi, const float* __restrict__ bias,
    const float* __restrict__ sinp, const float* __restrict__ cosp,
    __hip_bfloat16* __restrict__ o_q, __hip_bfloat16* __restrict__ o_k,
    __hip_bfloat16* __restrict__ o_vt, float* __restrict__ o_f32) {
  const int tid = threadIdx.x;
  const int w = tid >> 6, lane = tid & 63;
  const int wm = w >> 1, wn = w & 1;
  const int l15 = lane & 15, q4 = lane >> 4;
  const int mBase = blockIdx.y * 128, nBase = blockIdx.x * 128;

  __shared__ __hip_bfloat16 sm[2][3 * 4096]; // 2 bufs x three [128][32] tiles

  const char* p0 = (const char*)Ahi + (size_t)mBase * (KDIM * 2);
  const char* p1 = (const char*)Asec + (size_t)(SPLIT_A ? mBase : nBase) * (KDIM * 2);
  const char* p2 = (const char*)Bhi + (size_t)nBase * (KDIM * 2);

  const int slog = ((tid & 3) ^ ((tid >> 3) & 3)) << 4; // staged slot byte offset
  const int ph = ((q4 ^ ((l15 >> 1) & 3)) << 4);        // fragment slot byte offset

  auto stage = [&](int kt, int buf) {
    const int kofs = kt * 64; // bytes into each row
    char* base = (char*)sm[buf];
#pragma unroll
    for (int i = 0; i < 2; ++i) {
      const int c = i * 256 + tid; // 16B chunk index, 512 per tile
      const size_t rb = (size_t)(i * 64 + (tid >> 2)) * (KDIM * 2) + slog + kofs;
      gl16(p0 + rb, base + (size_t)c * 16);
      gl16(p1 + rb, base + 8192 + (size_t)c * 16);
      gl16(p2 + rb, base + 16384 + (size_t)c * 16);
    }
  };

  f32x4 acc[4][4] = {};

  stage(0, 0);
  __syncthreads();

  constexpr int NKT = KDIM / 32; // 24
  for (int kt = 0; kt < NKT; ++kt) {
    const int cur = kt & 1;
    if (kt + 1 < NKT) stage(kt + 1, cur ^ 1); // async; flies under compute
    char* s0 = (char*)sm[cur];
    char* s1 = s0 + 8192;
    char* s2 = s0 + 16384;
    bf16x8 a0[4], a1[4], b0[4], b1[4];
#pragma unroll
    for (int mt = 0; mt < 4; ++mt) {
      const int r = wm * 64 + mt * 16 + l15;
      a0[mt] = *(const bf16x8*)(s0 + r * 64 + ph);
      if (SPLIT_A) a1[mt] = *(const bf16x8*)(s1 + r * 64 + ph);
    }
#pragma unroll
    for (int nt = 0; nt < 4; ++nt) {
      const int r = wn * 64 + nt * 16 + l15;
      b0[nt] = *(const bf16x8*)(s2 + r * 64 + ph);
      if (!SPLIT_A) b1[nt] = *(const bf16x8*)(s1 + r * 64 + ph);
    }
    __builtin_amdgcn_s_setprio(1);
#pragma unroll
    for (int mt = 0; mt < 4; ++mt)
#pragma unroll
      for (int nt = 0; nt < 4; ++nt) {
        acc[mt][nt] = mfma_bf16(a0[mt], b0[nt], acc[mt][nt]);
        if (SPLIT_A)
          acc[mt][nt] = mfma_bf16(a1[mt], b0[nt], acc[mt][nt]);
        else
          acc[mt][nt] = mfma_bf16(a0[mt], b1[nt], acc[mt][nt]);
      }
    __builtin_amdgcn_s_setprio(0);
    __syncthreads(); // drains vmcnt -> buf[cur^1] complete; buf[cur] reusable
  }

  // epilogue; C layout: col = lane&15, row = 4*(lane>>4)+j
#pragma unroll
  for (int mt = 0; mt < 4; ++mt)
#pragma unroll
    for (int j = 0; j < 4; ++j) {
      const int gm = mBase + wm * 64 + mt * 16 + q4 * 4 + j;
      if (gm >= M) continue;
      if (EPI == 0) {
        const int b = gm / NTOK;
        const int t = gm - b * NTOK;
#pragma unroll
        for (int nt = 0; nt < 4; ++nt) {
          const int gc = nBase + wn * 64 + nt * 16 + l15;
          float v = acc[mt][nt][j] + bias[gc];
          const int three = gc / 768;
          const int hd = gc - three * 768;
          const int h = hd >> 6, d = hd & 63;
          const int bh = b * 12 + h;
          if (three == 2) {
            o_vt[((size_t)bh * 64 + d) * NKVPAD + t] = __float2bfloat16(v);
          } else {
            if (t > 0) {
              const float pv = acc[mt][nt ^ 2][j] + bias[gc ^ 32];
              const int so = (t - 1) * 64 + d;
              v = v * cosp[so] + ((d < 32) ? -pv : pv) * sinp[so];
            }
            if (three == 0)
              o_q[((size_t)bh * NTOK + t) * 64 + d] = __float2bfloat16(v);
            else  // K: fold softmax scale * log2(e) here (bf16 rel-err scale-invariant)
              o_k[((size_t)bh * NTOK + t) * 64 + d] = __float2bfloat16(v * SCALEL2);
          }
        }
      } else {
#pragma unroll
        for (int nt = 0; nt < 4; ++nt) {
          const int gc = nBase + wn * 64 + nt * 16 + l15;
          o_f32[(size_t)gm * 768 + gc] = acc[mt][nt][j] + bias[gc];
        }
      }
    }
}

// ===== K2: flash attention, 4 waves x 32 q-rows, KV tiles of 64 =====
// Grid: 864 = 8 XCD chunks * 12 heads * 9 q-blocks (XCD-aware remap keeps one
// head's K/V inside one XCD's L2). K is pre-scaled by 64^-0.5*log2e, so QK^T
// emerges in log2 domain. Common path is SHUFFLE-FREE: per-lane col-max +
// __all() implements the defer-max test across the wave; the l-sum is kept as
// per-lane partials and reduced once at the end. Slow path (first tile + rare
// max growth) does the 4-shfl row reduce + rescale. Tile kt=16 is the masked
// tail. PHASE-STAGGER: online softmax is order-independent, so each wave
// starts its KV loop at a different tile — co-resident waves occupy different
// pipes (MFMA / trans / LDS / mem) instead of convoying in lockstep.
__global__ __launch_bounds__(256) void k_attn(
    const __hip_bfloat16* __restrict__ Q, const __hip_bfloat16* __restrict__ Kk,
    const __hip_bfloat16* __restrict__ VT, __hip_bfloat16* __restrict__ ao) {
  __shared__ __hip_bfloat16 Pl[4][32][72]; // per-wave P tile
  const int tid = threadIdx.x, w = tid >> 6, lane = tid & 63;
  const int l15 = lane & 15, q4 = lane >> 4;
  const int id = blockIdx.x;
  const int xcd = id & 7, sub = id >> 3;   // sub 0..107
  const int hh = sub / 9;                  // head-within-xcd 0..11
  const int bh = xcd * 12 + hh;
  const int qb = (sub - hh * 9) * 128 + w * 32;
  const size_t qbase = (size_t)bh * NTOK * 64;
  const __hip_bfloat16* Kb = Kk + qbase;
  const __hip_bfloat16* Vb = VT + (size_t)bh * 64 * NKVPAD;

  // Q fragments (rows clamped; pad rows are discarded at store)
  bf16x8 qa[2][2];
#pragma unroll
  for (int mt = 0; mt < 2; ++mt) {
    int t = qb + mt * 16 + l15;
    if (t > NTOK - 1) t = NTOK - 1;
#pragma unroll
    for (int ks = 0; ks < 2; ++ks)
      qa[mt][ks] = *(const bf16x8*)(Q + qbase + (size_t)t * 64 + ks * 32 + q4 * 8);
  }

  f32x4 accO[2][4] = {};
  float mrun[2][4], lpart[2][4];
#pragma unroll
  for (int mt = 0; mt < 2; ++mt)
#pragma unroll
    for (int j = 0; j < 4; ++j) {
      mrun[mt][j] = -1e30f;
      lpart[mt][j] = 0.0f;
    }

  auto step = [&](int kt, bool last) {
    const int kb0 = kt * 64;
    // S = Q K^T, already in log2 domain (K pre-scaled)
    f32x4 s[2][4] = {};
    {
      bf16x8 kfr[2][4];
#pragma unroll
      for (int nt = 0; nt < 4; ++nt) {
        int krow = kb0 + nt * 16 + l15;
        if (last && krow > NTOK - 1) krow = NTOK - 1;
#pragma unroll
        for (int ks = 0; ks < 2; ++ks)
          kfr[ks][nt] = *(const bf16x8*)(Kb + (size_t)krow * 64 + ks * 32 + q4 * 8);
      }
      __builtin_amdgcn_s_setprio(1);
#pragma unroll
      for (int mt = 0; mt < 2; ++mt)
#pragma unroll
        for (int nt = 0; nt < 4; ++nt)
#pragma unroll
          for (int ks = 0; ks < 2; ++ks)
            s[mt][nt] = mfma_bf16(qa[mt][ks], kfr[ks][nt], s[mt][nt]);
      __builtin_amdgcn_s_setprio(0);
    }
    // mask dead key columns on the masked tail tile
    if (last) {
#pragma unroll
      for (int nt = 0; nt < 4; ++nt)
        if (kb0 + nt * 16 + l15 > NTOK - 1) {
#pragma unroll
          for (int mt = 0; mt < 2; ++mt)
#pragma unroll
            for (int j = 0; j < 4; ++j) s[mt][nt][j] = -1e30f;
        }
    }
    // shuffle-free defer-max test: lane-local col max vs mrun+8, __all()
    float smax[2][4];
    bool okl = true;
#pragma unroll
    for (int mt = 0; mt < 2; ++mt)
#pragma unroll
      for (int j = 0; j < 4; ++j) {
        const float a =
            fmaxf(fmaxf(s[mt][0][j], s[mt][1][j]), fmaxf(s[mt][2][j], s[mt][3][j]));
        smax[mt][j] = a;
        okl = okl && (a <= mrun[mt][j] + 8.0f);
      }
    if (!__all((int)okl)) {
      // slow path: true row max via 4-shfl reduce, then rescale state
#pragma unroll
      for (int mt = 0; mt < 2; ++mt)
#pragma unroll
        for (int j = 0; j < 4; ++j) {
          float m0 = smax[mt][j];
#pragma unroll
          for (int off = 1; off < 16; off <<= 1) m0 = fmaxf(m0, __shfl_xor(m0, off));
          const float mnew = fmaxf(mrun[mt][j], m0);
          const float fsc = exp2f(mrun[mt][j] - mnew);
          lpart[mt][j] *= fsc;
          mrun[mt][j] = mnew;
#pragma unroll
          for (int nd = 0; nd < 4; ++nd) accO[mt][nd][j] *= fsc;
        }
    }
    // P = exp2(S - m); per-lane partial sums; stage P to LDS for PV transpose
#pragma unroll
    for (int mt = 0; mt < 2; ++mt)
#pragma unroll
      for (int j = 0; j < 4; ++j) {
        const int row = mt * 16 + q4 * 4 + j;
        float acc = 0.0f;
#pragma unroll
        for (int nt = 0; nt < 4; ++nt) {
          const float p = exp2f(s[mt][nt][j] - mrun[mt][j]);
          acc += p;
          Pl[w][row][nt * 16 + l15] = __float2bfloat16(p);
        }
        lpart[mt][j] += acc;
      }
    // PV (wave-private LDS; compiler orders ds_write->ds_read via lgkmcnt)
    bf16x8 pa[2][2], vf[2][4];
#pragma unroll
    for (int mt = 0; mt < 2; ++mt)
#pragma unroll
      for (int ks = 0; ks < 2; ++ks)
        pa[mt][ks] = *(const bf16x8*)&Pl[w][mt * 16 + l15][ks * 32 + q4 * 8];
#pragma unroll
    for (int nd = 0; nd < 4; ++nd)
#pragma unroll
      for (int ks = 0; ks < 2; ++ks)
        vf[ks][nd] = *(const bf16x8*)(Vb + (size_t)(nd * 16 + l15) * NKVPAD + kb0 +
                                      ks * 32 + q4 * 8);
    __builtin_amdgcn_s_setprio(1);
#pragma unroll
    for (int mt = 0; mt < 2; ++mt)
#pragma unroll
      for (int nd = 0; nd < 4; ++nd)
#pragma unroll
        for (int ks = 0; ks < 2; ++ks)
          accO[mt][nd] = mfma_bf16(pa[mt][ks], vf[ks][nd], accO[mt][nd]);
    __builtin_amdgcn_s_setprio(0);
  };

  // phase-staggered cyclic walk over the 17 KV tiles
  const int off = ((w + (id & 3)) * 4) % 17;
  for (int i = 0; i < 17; ++i) {
    int kt = i + off;
    if (kt >= 17) kt -= 17;
    step(kt, kt == 16);
  }

  // epilogue: one 4-shfl reduce of the deferred l-sum, then store
  const int b = bh / 12, h = bh - (bh / 12) * 12;
#pragma unroll
  for (int mt = 0; mt < 2; ++mt)
#pragma unroll
    for (int j = 0; j < 4; ++j) {
      float sum = lpart[mt][j];
#pragma unroll
      for (int off2 = 1; off2 < 16; off2 <<= 1) sum += __shfl_xor(sum, off2);
      const int t = qb + mt * 16 + q4 * 4 + j;
      if (t > NTOK - 1) continue;
      const float inv = 1.0f / sum;
      const size_t ro = ((size_t)(b * NTOK + t)) * 768 + h * 64;
#pragma unroll
      for (int nd = 0; nd < 4; ++nd) {
        const int d = nd * 16 + l15;
        ao[ro + d] = __float2bfloat16(accO[mt][nd][j] * inv);
      }
    }
}

extern "C" void kernel_launch(void* const* d_in, const int* in_sizes, int n_in,
                              void* d_out, int out_size, void* d_ws, size_t ws_size,
                              hipStream_t stream) {
  const float* x = (const float*)d_in[0];
  const float* sinp = (const float*)d_in[1];
  const float* cosp = (const float*)d_in[2];
  const float* qkvw = (const float*)d_in[3];
  const float* qkvb = (const float*)d_in[4];
  const float* projw = (const float*)d_in[5];
  const float* projb = (const float*)d_in[6];

  char* ws = (char*)d_ws;
  __hip_bfloat16* xhi = (__hip_bfloat16*)(ws + OFF_XHI);
  __hip_bfloat16* xlo = (__hip_bfloat16*)(ws + OFF_XLO);
  __hip_bfloat16* wqhi = (__hip_bfloat16*)(ws + OFF_WQHI);
  __hip_bfloat16* pwhi = (__hip_bfloat16*)(ws + OFF_PWHI);
  __hip_bfloat16* pwlo = (__hip_bfloat16*)(ws + OFF_PWLO);
  __hip_bfloat16* qb = (__hip_bfloat16*)(ws + OFF_Q);
  __hip_bfloat16* kb = (__hip_bfloat16*)(ws + OFF_K);
  __hip_bfloat16* vt = (__hip_bfloat16*)(ws + OFF_VT);
  __hip_bfloat16* ao = (__hip_bfloat16*)(ws + OFF_AO);

  // K0: converts (x gets zero tail to MP rows; qkv_w hi only; proj_w hi+lo)
  {
    int n_src = M * KDIM, n_dst = MP * KDIM;
    k_split<<<(n_dst + 255) / 256, 256, 0, stream>>>(x, xhi, xlo, n_src, n_dst);
    int nw = NQKV * KDIM;
    k_tobf16<<<(nw + 255) / 256, 256, 0, stream>>>(qkvw, wqhi, nw);
    int np = KDIM * KDIM;
    k_split<<<(np + 255) / 256, 256, 0, stream>>>(projw, pwhi, pwlo, np, np);
    int nz = 96 * 64 * (NKVPAD - NTOK);
    k_zero_vt<<<(nz + 255) / 256, 256, 0, stream>>>(vt);
  }
  // K1: QKV GEMM (x split, w single) + bias + RoPE -> q, k(scaled), vT
  k_gemm<0, true><<<dim3(NQKV / 128, MP / 128), 256, 0, stream>>>(
      xhi, xlo, wqhi, qkvb, sinp, cosp, qb, kb, vt, nullptr);
  // K2: flash attention -> attn_out bf16 (864 = 8 XCD * 12 heads * 9 qblocks)
  k_attn<<<dim3(864), 256, 0, stream>>>(qb, kb, vt, ao);
  // K3: proj GEMM (attn_out single, w split) + bias -> fp32 out
  k_gemm<1, false><<<dim3(KDIM / 128, MP / 128), 256, 0, stream>>>(
      ao, pwlo, pwhi, projb, nullptr, nullptr, nullptr, nullptr, nullptr,
      (float*)d_out);
}

// Round 8
// 260.592 us; speedup vs baseline: 1.1255x; 1.1255x over previous
//
#include <hip/hip_runtime.h>
#include <hip/hip_bf16.h>

// ===== Problem constants =====
// B=8, N=1025, C=768, H=12, HD=64
constexpr int NTOK   = 1025;
constexpr int M      = 8 * NTOK;      // 8200 tokens
constexpr int MP     = 8320;          // 65 * 128 padded rows
constexpr int KDIM   = 768;
constexpr int NQKV   = 2304;
constexpr int NKVPAD = 1088;          // 17*64 padded kv length for vT
constexpr float SCALEL2 = 0.125f * 1.44269504f; // 64^-0.5 * log2(e), folded into K

using bf16x8 = __attribute__((ext_vector_type(8))) short;
using f32x4  = __attribute__((ext_vector_type(4))) float;

__device__ __forceinline__ f32x4 mfma_bf16(bf16x8 a, bf16x8 b, f32x4 c) {
  return __builtin_amdgcn_mfma_f32_16x16x32_bf16(a, b, c, 0, 0, 0);
}

__device__ __forceinline__ void gl16(const void* g, void* l) {
  __builtin_amdgcn_global_load_lds(
      (const __attribute__((address_space(1))) void*)g,
      (__attribute__((address_space(3))) void*)l, 16, 0, 0);
}

// ===== Workspace layout (bytes), all 256-aligned =====
constexpr size_t SZ_X     = (size_t)MP * KDIM * 2;        // 12,779,520
constexpr size_t SZ_WQ    = (size_t)NQKV * KDIM * 2;      // 3,538,944
constexpr size_t SZ_PW    = (size_t)KDIM * KDIM * 2;      // 1,179,648
constexpr size_t SZ_QK    = (size_t)96 * NTOK * 64 * 2;   // 12,595,200
constexpr size_t SZ_VT    = (size_t)96 * 64 * NKVPAD * 2; // 13,369,344
constexpr size_t OFF_XHI  = 0;
constexpr size_t OFF_XLO  = OFF_XHI + SZ_X;
constexpr size_t OFF_WQHI = OFF_XLO + SZ_X;
constexpr size_t OFF_PWHI = OFF_WQHI + SZ_WQ;
constexpr size_t OFF_PWLO = OFF_PWHI + SZ_PW;
constexpr size_t OFF_Q    = OFF_PWLO + SZ_PW;
constexpr size_t OFF_K    = OFF_Q + SZ_QK;
constexpr size_t OFF_VT   = OFF_K + SZ_QK;
constexpr size_t OFF_AO   = OFF_VT + SZ_VT;
// total ~83 MB

// ===== K0a: fp32 -> (hi,lo) bf16 split, zero tail =====
__global__ void k_split(const float* __restrict__ src, __hip_bfloat16* __restrict__ hi,
                        __hip_bfloat16* __restrict__ lo, int n_src, int n_dst) {
  int i = blockIdx.x * 256 + threadIdx.x;
  if (i >= n_dst) return;
  float v = (i < n_src) ? src[i] : 0.0f;
  __hip_bfloat16 h = __float2bfloat16(v);
  hi[i] = h;
  lo[i] = __float2bfloat16(v - __bfloat162float(h));
}

// K0b: fp32 -> bf16 (hi only)
__global__ void k_tobf16(const float* __restrict__ src, __hip_bfloat16* __restrict__ dst,
                         int n) {
  int i = blockIdx.x * 256 + threadIdx.x;
  if (i >= n) return;
  dst[i] = __float2bfloat16(src[i]);
}

// zero vT pad columns (keys 1025..1087) so PV MFMA never sees NaN garbage
__global__ void k_zero_vt(__hip_bfloat16* __restrict__ vt) {
  int i = blockIdx.x * 256 + threadIdx.x;
  constexpr int NPADC = NKVPAD - NTOK; // 63
  if (i >= 96 * 64 * NPADC) return;
  int r = i / NPADC;
  int c = NTOK + (i - r * NPADC);
  vt[(size_t)r * NKVPAD + c] = __float2bfloat16(0.0f);
}

// ===== GEMM core: 128x128 tile, BK=32, 2-term split, swizzled LDS =====
// 2-phase double-buffered staging: stage(t+1) is issued BEFORE compute(t);
// the single __syncthreads per step drains only the latency tail that the
// 32 MFMAs + 12 ds_read_b128 didn't already cover (T3 minimal recipe).
// SPLIT_A=1: acc = Ah*Bh + Al*Bh   (Asec = A_lo, row base mBase)
// SPLIT_A=0: acc = Ah*Bh + Ah*Bl   (Asec = B_lo, row base nBase)
// LDS swizzle (conflict-free ds_read_b128 with linear global_load_lds dest):
//   chunk c (16B) holds global (row=c>>2, slot=(c&3)^((row>>1)&3)) of the tile;
//   4-lane groups still fetch the same contiguous 64B from global (coalesced).
// EPI=0: QKV -> bias + RoPE -> q,k ([bh][t][d] bf16; K pre-scaled by SCALEL2)
//        and vT ([bh][d][t_pad] bf16)
// EPI=1: proj -> bias -> fp32 d_out
template <int EPI, bool SPLIT_A>
__global__ __launch_bounds__(256) void k_gemm(
    const __hip_bfloat16* __restrict__ Ahi, const __hip_bfloat16* __restrict__ Asec,
    const __hip_bfloat16* __restrict__ Bhi, const float* __restrict__ bias,
    const float* __restrict__ sinp, const float* __restrict__ cosp,
    __hip_bfloat16* __restrict__ o_q, __hip_bfloat16* __restrict__ o_k,
    __hip_bfloat16* __restrict__ o_vt, float* __restrict__ o_f32) {
  const int tid = threadIdx.x;
  const int w = tid >> 6, lane = tid & 63;
  const int wm = w >> 1, wn = w & 1;
  const int l15 = lane & 15, q4 = lane >> 4;
  const int mBase = blockIdx.y * 128, nBase = blockIdx.x * 128;

  __shared__ __hip_bfloat16 sm[2][3 * 4096]; // 2 bufs x three [128][32] tiles

  const char* p0 = (const char*)Ahi + (size_t)mBase * (KDIM * 2);
  const char* p1 = (const char*)Asec + (size_t)(SPLIT_A ? mBase : nBase) * (KDIM * 2);
  const char* p2 = (const char*)Bhi + (size_t)nBase * (KDIM * 2);

  const int slog = ((tid & 3) ^ ((tid >> 3) & 3)) << 4; // staged slot byte offset
  const int ph = ((q4 ^ ((l15 >> 1) & 3)) << 4);        // fragment slot byte offset

  auto stage = [&](int kt, int buf) {
    const int kofs = kt * 64; // bytes into each row
    char* base = (char*)sm[buf];
#pragma unroll
    for (int i = 0; i < 2; ++i) {
      const int c = i * 256 + tid; // 16B chunk index, 512 per tile
      const size_t rb = (size_t)(i * 64 + (tid >> 2)) * (KDIM * 2) + slog + kofs;
      gl16(p0 + rb, base + (size_t)c * 16);
      gl16(p1 + rb, base + 8192 + (size_t)c * 16);
      gl16(p2 + rb, base + 16384 + (size_t)c * 16);
    }
  };

  f32x4 acc[4][4] = {};

  stage(0, 0);
  __syncthreads();

  constexpr int NKT = KDIM / 32; // 24
  for (int kt = 0; kt < NKT; ++kt) {
    const int cur = kt & 1;
    if (kt + 1 < NKT) stage(kt + 1, cur ^ 1); // async; flies under compute
    char* s0 = (char*)sm[cur];
    char* s1 = s0 + 8192;
    char* s2 = s0 + 16384;
    bf16x8 a0[4], a1[4], b0[4], b1[4];
#pragma unroll
    for (int mt = 0; mt < 4; ++mt) {
      const int r = wm * 64 + mt * 16 + l15;
      a0[mt] = *(const bf16x8*)(s0 + r * 64 + ph);
      if (SPLIT_A) a1[mt] = *(const bf16x8*)(s1 + r * 64 + ph);
    }
#pragma unroll
    for (int nt = 0; nt < 4; ++nt) {
      const int r = wn * 64 + nt * 16 + l15;
      b0[nt] = *(const bf16x8*)(s2 + r * 64 + ph);
      if (!SPLIT_A) b1[nt] = *(const bf16x8*)(s1 + r * 64 + ph);
    }
    __builtin_amdgcn_s_setprio(1);
#pragma unroll
    for (int mt = 0; mt < 4; ++mt)
#pragma unroll
      for (int nt = 0; nt < 4; ++nt) {
        acc[mt][nt] = mfma_bf16(a0[mt], b0[nt], acc[mt][nt]);
        if (SPLIT_A)
          acc[mt][nt] = mfma_bf16(a1[mt], b0[nt], acc[mt][nt]);
        else
          acc[mt][nt] = mfma_bf16(a0[mt], b1[nt], acc[mt][nt]);
      }
    __builtin_amdgcn_s_setprio(0);
    __syncthreads(); // drains vmcnt -> buf[cur^1] complete; buf[cur] reusable
  }

  // epilogue; C layout: col = lane&15, row = 4*(lane>>4)+j
#pragma unroll
  for (int mt = 0; mt < 4; ++mt)
#pragma unroll
    for (int j = 0; j < 4; ++j) {
      const int gm = mBase + wm * 64 + mt * 16 + q4 * 4 + j;
      if (gm >= M) continue;
      if (EPI == 0) {
        const int b = gm / NTOK;
        const int t = gm - b * NTOK;
#pragma unroll
        for (int nt = 0; nt < 4; ++nt) {
          const int gc = nBase + wn * 64 + nt * 16 + l15;
          float v = acc[mt][nt][j] + bias[gc];
          const int three = gc / 768;
          const int hd = gc - three * 768;
          const int h = hd >> 6, d = hd & 63;
          const int bh = b * 12 + h;
          if (three == 2) {
            o_vt[((size_t)bh * 64 + d) * NKVPAD + t] = __float2bfloat16(v);
          } else {
            if (t > 0) {
              const float pv = acc[mt][nt ^ 2][j] + bias[gc ^ 32];
              const int so = (t - 1) * 64 + d;
              v = v * cosp[so] + ((d < 32) ? -pv : pv) * sinp[so];
            }
            if (three == 0)
              o_q[((size_t)bh * NTOK + t) * 64 + d] = __float2bfloat16(v);
            else  // K: fold softmax scale * log2(e) here (bf16 rel-err scale-invariant)
              o_k[((size_t)bh * NTOK + t) * 64 + d] = __float2bfloat16(v * SCALEL2);
          }
        }
      } else {
#pragma unroll
        for (int nt = 0; nt < 4; ++nt) {
          const int gc = nBase + wn * 64 + nt * 16 + l15;
          o_f32[(size_t)gm * 768 + gc] = acc[mt][nt][j] + bias[gc];
        }
      }
    }
}

// ===== K2: flash attention, 4 waves x 32 q-rows, KV tiles of 64 =====
// Grid: 864 = 8 XCD chunks * 12 heads * 9 q-blocks. K/V tiles are staged in
// LDS once per BLOCK (shared by the 4 waves), double-buffered, via
// global_load_lds with chunk-XOR swizzle (linear LDS dest + pre-swizzled
// global source chunk^=(row&7); read side applies the same XOR -> <=2-way
// bank aliasing on ds_read_b128, which is free). This replaces 64 strided
// 16-transaction global loads per step per block with one coalesced 16 KB
// staged fetch. Softmax: K pre-scaled by 64^-0.5*log2e (log2 domain);
// shuffle-free defer-max; deferred l-sum; masked tail tile kt=16.
__global__ __launch_bounds__(256) void k_attn(
    const __hip_bfloat16* __restrict__ Q, const __hip_bfloat16* __restrict__ Kk,
    const __hip_bfloat16* __restrict__ VT, __hip_bfloat16* __restrict__ ao) {
  __shared__ __hip_bfloat16 Kt[2][64 * 64]; // [key-row][d] swizzled, 8KB/buf
  __shared__ __hip_bfloat16 Vt[2][64 * 64]; // [d-row][key] swizzled, 8KB/buf
  __shared__ __hip_bfloat16 Pl[4][32][72];  // per-wave P tile
  const int tid = threadIdx.x, w = tid >> 6, lane = tid & 63;
  const int l15 = lane & 15, q4 = lane >> 4;
  const int id = blockIdx.x;
  const int xcd = id & 7, sub = id >> 3;   // sub 0..107
  const int hh = sub / 9;                  // head-within-xcd 0..11
  const int bh = xcd * 12 + hh;
  const int qb = (sub - hh * 9) * 128 + w * 32;
  const size_t qbase = (size_t)bh * NTOK * 64;
  const char* Kb = (const char*)(Kk + qbase);
  const char* Vb = (const char*)(VT + (size_t)bh * 64 * NKVPAD);

  // Q fragments (rows clamped; pad rows are discarded at store)
  bf16x8 qa[2][2];
#pragma unroll
  for (int mt = 0; mt < 2; ++mt) {
    int t = qb + mt * 16 + l15;
    if (t > NTOK - 1) t = NTOK - 1;
#pragma unroll
    for (int ks = 0; ks < 2; ++ks)
      qa[mt][ks] = *(const bf16x8*)(Q + qbase + (size_t)t * 64 + ks * 32 + q4 * 8);
  }

  f32x4 accO[2][4] = {};
  float mrun[2][4], lpart[2][4];
#pragma unroll
  for (int mt = 0; mt < 2; ++mt)
#pragma unroll
    for (int j = 0; j < 4; ++j) {
      mrun[mt][j] = -1e30f;
      lpart[mt][j] = 0.0f;
    }

  // stage K/V tile kt into buffer b: 512 16B chunks each, 2 per thread;
  // LDS chunk c = (row = c>>3, phys = c&7) holds source chunk phys^(row&7)
  auto stageKV = [&](int kt, int b) {
    const int kb0 = kt * 64;
#pragma unroll
    for (int i = 0; i < 2; ++i) {
      const int c = i * 256 + tid;
      const int row = c >> 3;
      const int schunk = (c & 7) ^ (row & 7);
      const int srow = min(kb0 + row, NTOK - 1); // clamp; masked in scores
      gl16(Kb + (size_t)srow * 128 + schunk * 16, (char*)&Kt[b][0] + (size_t)c * 16);
      gl16(Vb + (size_t)row * (NKVPAD * 2) + (size_t)kb0 * 2 + schunk * 16,
           (char*)&Vt[b][0] + (size_t)c * 16);
    }
  };

  auto step = [&](int kt, int cur, bool last) {
    const int kb0 = kt * 64;
    // S = Q K^T from LDS (swizzled read), already in log2 domain
    f32x4 s[2][4] = {};
    {
      bf16x8 kfr[2][4];
#pragma unroll
      for (int nt = 0; nt < 4; ++nt) {
        const int row = nt * 16 + l15;
#pragma unroll
        for (int ks = 0; ks < 2; ++ks)
          kfr[ks][nt] = *(const bf16x8*)((const char*)&Kt[cur][0] + row * 128 +
                                         (((ks * 4 + q4) ^ (row & 7)) << 4));
      }
      __builtin_amdgcn_s_setprio(1);
#pragma unroll
      for (int mt = 0; mt < 2; ++mt)
#pragma unroll
        for (int nt = 0; nt < 4; ++nt)
#pragma unroll
          for (int ks = 0; ks < 2; ++ks)
            s[mt][nt] = mfma_bf16(qa[mt][ks], kfr[ks][nt], s[mt][nt]);
      __builtin_amdgcn_s_setprio(0);
    }
    // mask dead key columns on the masked tail tile
    if (last) {
#pragma unroll
      for (int nt = 0; nt < 4; ++nt)
        if (kb0 + nt * 16 + l15 > NTOK - 1) {
#pragma unroll
          for (int mt = 0; mt < 2; ++mt)
#pragma unroll
            for (int j = 0; j < 4; ++j) s[mt][nt][j] = -1e30f;
        }
    }
    // shuffle-free defer-max test: lane-local col max vs mrun+8, __all()
    float smax[2][4];
    bool okl = true;
#pragma unroll
    for (int mt = 0; mt < 2; ++mt)
#pragma unroll
      for (int j = 0; j < 4; ++j) {
        const float a =
            fmaxf(fmaxf(s[mt][0][j], s[mt][1][j]), fmaxf(s[mt][2][j], s[mt][3][j]));
        smax[mt][j] = a;
        okl = okl && (a <= mrun[mt][j] + 8.0f);
      }
    if (!__all((int)okl)) {
      // slow path: true row max via 4-shfl reduce, then rescale state
#pragma unroll
      for (int mt = 0; mt < 2; ++mt)
#pragma unroll
        for (int j = 0; j < 4; ++j) {
          float m0 = smax[mt][j];
#pragma unroll
          for (int off = 1; off < 16; off <<= 1) m0 = fmaxf(m0, __shfl_xor(m0, off));
          const float mnew = fmaxf(mrun[mt][j], m0);
          const float fsc = exp2f(mrun[mt][j] - mnew);
          lpart[mt][j] *= fsc;
          mrun[mt][j] = mnew;
#pragma unroll
          for (int nd = 0; nd < 4; ++nd) accO[mt][nd][j] *= fsc;
        }
    }
    // P = exp2(S - m); per-lane partial sums; stage P to LDS for PV transpose
#pragma unroll
    for (int mt = 0; mt < 2; ++mt)
#pragma unroll
      for (int j = 0; j < 4; ++j) {
        const int row = mt * 16 + q4 * 4 + j;
        float acc = 0.0f;
#pragma unroll
        for (int nt = 0; nt < 4; ++nt) {
          const float p = exp2f(s[mt][nt][j] - mrun[mt][j]);
          acc += p;
          Pl[w][row][nt * 16 + l15] = __float2bfloat16(p);
        }
        lpart[mt][j] += acc;
      }
    // PV; V fragments from swizzled LDS (wave-private Pl ordered by lgkmcnt)
    bf16x8 pa[2][2], vf[2][4];
#pragma unroll
    for (int mt = 0; mt < 2; ++mt)
#pragma unroll
      for (int ks = 0; ks < 2; ++ks)
        pa[mt][ks] = *(const bf16x8*)&Pl[w][mt * 16 + l15][ks * 32 + q4 * 8];
#pragma unroll
    for (int nd = 0; nd < 4; ++nd) {
      const int row = nd * 16 + l15;
#pragma unroll
      for (int ks = 0; ks < 2; ++ks)
        vf[ks][nd] = *(const bf16x8*)((const char*)&Vt[cur][0] + row * 128 +
                                      (((ks * 4 + q4) ^ (row & 7)) << 4));
    }
    __builtin_amdgcn_s_setprio(1);
#pragma unroll
    for (int mt = 0; mt < 2; ++mt)
#pragma unroll
      for (int nd = 0; nd < 4; ++nd)
#pragma unroll
        for (int ks = 0; ks < 2; ++ks)
          accO[mt][nd] = mfma_bf16(pa[mt][ks], vf[ks][nd], accO[mt][nd]);
    __builtin_amdgcn_s_setprio(0);
  };

  stageKV(0, 0);
  __syncthreads();
  for (int kt = 0; kt < 17; ++kt) {
    const int cur = kt & 1;
    if (kt < 16) stageKV(kt + 1, cur ^ 1); // async; flies under compute
    step(kt, cur, kt == 16);
    __syncthreads(); // staging for kt+1 complete; buf[cur] reusable
  }

  // epilogue: one 4-shfl reduce of the deferred l-sum, then store
  const int b = bh / 12, h = bh - (bh / 12) * 12;
#pragma unroll
  for (int mt = 0; mt < 2; ++mt)
#pragma unroll
    for (int j = 0; j < 4; ++j) {
      float sum = lpart[mt][j];
#pragma unroll
      for (int off2 = 1; off2 < 16; off2 <<= 1) sum += __shfl_xor(sum, off2);
      const int t = qb + mt * 16 + q4 * 4 + j;
      if (t > NTOK - 1) continue;
      const float inv = 1.0f / sum;
      const size_t ro = ((size_t)(b * NTOK + t)) * 768 + h * 64;
#pragma unroll
      for (int nd = 0; nd < 4; ++nd) {
        const int d = nd * 16 + l15;
        ao[ro + d] = __float2bfloat16(accO[mt][nd][j] * inv);
      }
    }
}

extern "C" void kernel_launch(void* const* d_in, const int* in_sizes, int n_in,
                              void* d_out, int out_size, void* d_ws, size_t ws_size,
                              hipStream_t stream) {
  const float* x = (const float*)d_in[0];
  const float* sinp = (const float*)d_in[1];
  const float* cosp = (const float*)d_in[2];
  const float* qkvw = (const float*)d_in[3];
  const float* qkvb = (const float*)d_in[4];
  const float* projw = (const float*)d_in[5];
  const float* projb = (const float*)d_in[6];

  char* ws = (char*)d_ws;
  __hip_bfloat16* xhi = (__hip_bfloat16*)(ws + OFF_XHI);
  __hip_bfloat16* xlo = (__hip_bfloat16*)(ws + OFF_XLO);
  __hip_bfloat16* wqhi = (__hip_bfloat16*)(ws + OFF_WQHI);
  __hip_bfloat16* pwhi = (__hip_bfloat16*)(ws + OFF_PWHI);
  __hip_bfloat16* pwlo = (__hip_bfloat16*)(ws + OFF_PWLO);
  __hip_bfloat16* qb = (__hip_bfloat16*)(ws + OFF_Q);
  __hip_bfloat16* kb = (__hip_bfloat16*)(ws + OFF_K);
  __hip_bfloat16* vt = (__hip_bfloat16*)(ws + OFF_VT);
  __hip_bfloat16* ao = (__hip_bfloat16*)(ws + OFF_AO);

  // K0: converts (x gets zero tail to MP rows; qkv_w hi only; proj_w hi+lo)
  {
    int n_src = M * KDIM, n_dst = MP * KDIM;
    k_split<<<(n_dst + 255) / 256, 256, 0, stream>>>(x, xhi, xlo, n_src, n_dst);
    int nw = NQKV * KDIM;
    k_tobf16<<<(nw + 255) / 256, 256, 0, stream>>>(qkvw, wqhi, nw);
    int np = KDIM * KDIM;
    k_split<<<(np + 255) / 256, 256, 0, stream>>>(projw, pwhi, pwlo, np, np);
    int nz = 96 * 64 * (NKVPAD - NTOK);
    k_zero_vt<<<(nz + 255) / 256, 256, 0, stream>>>(vt);
  }
  // K1: QKV GEMM (x split, w single) + bias + RoPE -> q, k(scaled), vT
  k_gemm<0, true><<<dim3(NQKV / 128, MP / 128), 256, 0, stream>>>(
      xhi, xlo, wqhi, qkvb, sinp, cosp, qb, kb, vt, nullptr);
  // K2: flash attention -> attn_out bf16 (864 = 8 XCD * 12 heads * 9 qblocks)
  k_attn<<<dim3(864), 256, 0, stream>>>(qb, kb, vt, ao);
  // K3: proj GEMM (attn_out single, w split) + bias -> fp32 out
  k_gemm<1, false><<<dim3(KDIM / 128, MP / 128), 256, 0, stream>>>(
      ao, pwlo, pwhi, projb, nullptr, nullptr, nullptr, nullptr, nullptr,
      (float*)d_out);
}

// Round 9
// 254.126 us; speedup vs baseline: 1.1542x; 1.0254x over previous
//
#include <hip/hip_runtime.h>
#include <hip/hip_bf16.h>

// ===== Problem constants =====
// B=8, N=1025, C=768, H=12, HD=64
constexpr int NTOK   = 1025;
constexpr int M      = 8 * NTOK;      // 8200 tokens
constexpr int MP     = 8320;          // 65 * 128 padded rows
constexpr int KDIM   = 768;
constexpr int NQKV   = 2304;
constexpr int NKVPAD = 1088;          // 17*64 padded kv length for vT
constexpr float SCALEL2 = 0.125f * 1.44269504f; // 64^-0.5 * log2(e), folded into K

using bf16x8 = __attribute__((ext_vector_type(8))) short;
using f32x4  = __attribute__((ext_vector_type(4))) float;

__device__ __forceinline__ f32x4 mfma_bf16(bf16x8 a, bf16x8 b, f32x4 c) {
  return __builtin_amdgcn_mfma_f32_16x16x32_bf16(a, b, c, 0, 0, 0);
}

__device__ __forceinline__ void gl16(const void* g, void* l) {
  __builtin_amdgcn_global_load_lds(
      (const __attribute__((address_space(1))) void*)g,
      (__attribute__((address_space(3))) void*)l, 16, 0, 0);
}

// ===== Workspace layout (bytes), all 256-aligned =====
constexpr size_t SZ_X     = (size_t)MP * KDIM * 2;        // 12,779,520
constexpr size_t SZ_WQ    = (size_t)NQKV * KDIM * 2;      // 3,538,944
constexpr size_t SZ_PW    = (size_t)KDIM * KDIM * 2;      // 1,179,648
constexpr size_t SZ_QK    = (size_t)96 * NTOK * 64 * 2;   // 12,595,200
constexpr size_t SZ_VT    = (size_t)96 * 64 * NKVPAD * 2; // 13,369,344
constexpr size_t OFF_XHI  = 0;
constexpr size_t OFF_XLO  = OFF_XHI + SZ_X;
constexpr size_t OFF_WQHI = OFF_XLO + SZ_X;
constexpr size_t OFF_PWHI = OFF_WQHI + SZ_WQ;
constexpr size_t OFF_PWLO = OFF_PWHI + SZ_PW;
constexpr size_t OFF_Q    = OFF_PWLO + SZ_PW;
constexpr size_t OFF_K    = OFF_Q + SZ_QK;
constexpr size_t OFF_VT   = OFF_K + SZ_QK;
constexpr size_t OFF_AO   = OFF_VT + SZ_VT;
// total ~83 MB

// ===== K0a: fp32 -> (hi,lo) bf16 split, zero tail =====
__global__ void k_split(const float* __restrict__ src, __hip_bfloat16* __restrict__ hi,
                        __hip_bfloat16* __restrict__ lo, int n_src, int n_dst) {
  int i = blockIdx.x * 256 + threadIdx.x;
  if (i >= n_dst) return;
  float v = (i < n_src) ? src[i] : 0.0f;
  __hip_bfloat16 h = __float2bfloat16(v);
  hi[i] = h;
  lo[i] = __float2bfloat16(v - __bfloat162float(h));
}

// K0b: fp32 -> bf16 (hi only)
__global__ void k_tobf16(const float* __restrict__ src, __hip_bfloat16* __restrict__ dst,
                         int n) {
  int i = blockIdx.x * 256 + threadIdx.x;
  if (i >= n) return;
  dst[i] = __float2bfloat16(src[i]);
}

// zero vT pad columns (keys 1025..1087) so PV MFMA never sees NaN garbage
__global__ void k_zero_vt(__hip_bfloat16* __restrict__ vt) {
  int i = blockIdx.x * 256 + threadIdx.x;
  constexpr int NPADC = NKVPAD - NTOK; // 63
  if (i >= 96 * 64 * NPADC) return;
  int r = i / NPADC;
  int c = NTOK + (i - r * NPADC);
  vt[(size_t)r * NKVPAD + c] = __float2bfloat16(0.0f);
}

// ===== GEMM core: 128x128 tile, BK=32, 2-term split, swizzled LDS =====
// 1D grid + bijective XCD-chunk remap (T1/m204): hardware assigns XCD =
// dispatch_id % 8; the remap gives each XCD ~nwg/8 CONSECUTIVE logical tiles
// (x-fastest: 18 or 6 tiles share one A row-panel), so each A panel is
// fetched by exactly one XCD's L2 instead of all eight (was 5x over-fetch).
// 2-phase double-buffered staging: stage(t+1) issued BEFORE compute(t);
// single __syncthreads per step (T3 minimal recipe).
// SPLIT_A=1: acc = Ah*Bh + Al*Bh   (Asec = A_lo, row base mBase)
// SPLIT_A=0: acc = Ah*Bh + Ah*Bl   (Asec = B_lo, row base nBase)
// LDS swizzle (conflict-free ds_read_b128 with linear global_load_lds dest):
//   chunk c (16B) holds global (row=c>>2, slot=(c&3)^((row>>1)&3)) of the tile;
//   4-lane groups still fetch the same contiguous 64B from global (coalesced).
// EPI=0: QKV -> bias + RoPE -> q,k ([bh][t][d] bf16; K pre-scaled by SCALEL2)
//        and vT ([bh][d][t_pad] bf16)
// EPI=1: proj -> bias -> fp32 d_out
template <int EPI, bool SPLIT_A, int NBX>
__global__ __launch_bounds__(256) void k_gemm(
    const __hip_bfloat16* __restrict__ Ahi, const __hip_bfloat16* __restrict__ Asec,
    const __hip_bfloat16* __restrict__ Bhi, const float* __restrict__ bias,
    const float* __restrict__ sinp, const float* __restrict__ cosp,
    __hip_bfloat16* __restrict__ o_q, __hip_bfloat16* __restrict__ o_k,
    __hip_bfloat16* __restrict__ o_vt, float* __restrict__ o_f32) {
  const int tid = threadIdx.x;
  const int w = tid >> 6, lane = tid & 63;
  const int wm = w >> 1, wn = w & 1;
  const int l15 = lane & 15, q4 = lane >> 4;

  // bijective XCD-chunk remap (nwg may not divide by 8)
  const int nwg = gridDim.x;
  const int orig = blockIdx.x;
  const int qc = nwg >> 3, rc = nwg & 7;
  const int xcd = orig & 7, o8 = orig >> 3;
  const int wg =
      (xcd < rc ? xcd * (qc + 1) : rc * (qc + 1) + (xcd - rc) * qc) + o8;
  const int bx = wg % NBX, by = wg / NBX;
  const int mBase = by * 128, nBase = bx * 128;

  __shared__ __hip_bfloat16 sm[2][3 * 4096]; // 2 bufs x three [128][32] tiles

  const char* p0 = (const char*)Ahi + (size_t)mBase * (KDIM * 2);
  const char* p1 = (const char*)Asec + (size_t)(SPLIT_A ? mBase : nBase) * (KDIM * 2);
  const char* p2 = (const char*)Bhi + (size_t)nBase * (KDIM * 2);

  const int slog = ((tid & 3) ^ ((tid >> 3) & 3)) << 4; // staged slot byte offset
  const int ph = ((q4 ^ ((l15 >> 1) & 3)) << 4);        // fragment slot byte offset

  auto stage = [&](int kt, int buf) {
    const int kofs = kt * 64; // bytes into each row
    char* base = (char*)sm[buf];
#pragma unroll
    for (int i = 0; i < 2; ++i) {
      const int c = i * 256 + tid; // 16B chunk index, 512 per tile
      const size_t rb = (size_t)(i * 64 + (tid >> 2)) * (KDIM * 2) + slog + kofs;
      gl16(p0 + rb, base + (size_t)c * 16);
      gl16(p1 + rb, base + 8192 + (size_t)c * 16);
      gl16(p2 + rb, base + 16384 + (size_t)c * 16);
    }
  };

  f32x4 acc[4][4] = {};

  stage(0, 0);
  __syncthreads();

  constexpr int NKT = KDIM / 32; // 24
  for (int kt = 0; kt < NKT; ++kt) {
    const int cur = kt & 1;
    if (kt + 1 < NKT) stage(kt + 1, cur ^ 1); // async; flies under compute
    char* s0 = (char*)sm[cur];
    char* s1 = s0 + 8192;
    char* s2 = s0 + 16384;
    bf16x8 a0[4], a1[4], b0[4], b1[4];
#pragma unroll
    for (int mt = 0; mt < 4; ++mt) {
      const int r = wm * 64 + mt * 16 + l15;
      a0[mt] = *(const bf16x8*)(s0 + r * 64 + ph);
      if (SPLIT_A) a1[mt] = *(const bf16x8*)(s1 + r * 64 + ph);
    }
#pragma unroll
    for (int nt = 0; nt < 4; ++nt) {
      const int r = wn * 64 + nt * 16 + l15;
      b0[nt] = *(const bf16x8*)(s2 + r * 64 + ph);
      if (!SPLIT_A) b1[nt] = *(const bf16x8*)(s1 + r * 64 + ph);
    }
    __builtin_amdgcn_s_setprio(1);
#pragma unroll
    for (int mt = 0; mt < 4; ++mt)
#pragma unroll
      for (int nt = 0; nt < 4; ++nt) {
        acc[mt][nt] = mfma_bf16(a0[mt], b0[nt], acc[mt][nt]);
        if (SPLIT_A)
          acc[mt][nt] = mfma_bf16(a1[mt], b0[nt], acc[mt][nt]);
        else
          acc[mt][nt] = mfma_bf16(a0[mt], b1[nt], acc[mt][nt]);
      }
    __builtin_amdgcn_s_setprio(0);
    __syncthreads(); // drains vmcnt -> buf[cur^1] complete; buf[cur] reusable
  }

  // epilogue; C layout: col = lane&15, row = 4*(lane>>4)+j
#pragma unroll
  for (int mt = 0; mt < 4; ++mt)
#pragma unroll
    for (int j = 0; j < 4; ++j) {
      const int gm = mBase + wm * 64 + mt * 16 + q4 * 4 + j;
      if (gm >= M) continue;
      if (EPI == 0) {
        const int b = gm / NTOK;
        const int t = gm - b * NTOK;
#pragma unroll
        for (int nt = 0; nt < 4; ++nt) {
          const int gc = nBase + wn * 64 + nt * 16 + l15;
          float v = acc[mt][nt][j] + bias[gc];
          const int three = gc / 768;
          const int hd = gc - three * 768;
          const int h = hd >> 6, d = hd & 63;
          const int bh = b * 12 + h;
          if (three == 2) {
            o_vt[((size_t)bh * 64 + d) * NKVPAD + t] = __float2bfloat16(v);
          } else {
            if (t > 0) {
              const float pv = acc[mt][nt ^ 2][j] + bias[gc ^ 32];
              const int so = (t - 1) * 64 + d;
              v = v * cosp[so] + ((d < 32) ? -pv : pv) * sinp[so];
            }
            if (three == 0)
              o_q[((size_t)bh * NTOK + t) * 64 + d] = __float2bfloat16(v);
            else  // K: fold softmax scale * log2(e) here (bf16 rel-err scale-invariant)
              o_k[((size_t)bh * NTOK + t) * 64 + d] = __float2bfloat16(v * SCALEL2);
          }
        }
      } else {
#pragma unroll
        for (int nt = 0; nt < 4; ++nt) {
          const int gc = nBase + wn * 64 + nt * 16 + l15;
          o_f32[(size_t)gm * 768 + gc] = acc[mt][nt][j] + bias[gc];
        }
      }
    }
}

// ===== K2: flash attention, 4 waves x 32 q-rows, KV tiles of 64 =====
// Grid: 864 = 8 XCD chunks * 12 heads * 9 q-blocks. K/V tiles are staged in
// LDS once per BLOCK (shared by the 4 waves), double-buffered, via
// global_load_lds with chunk-XOR swizzle (linear LDS dest + pre-swizzled
// global source chunk^=(row&7); read side applies the same XOR -> <=2-way
// bank aliasing on ds_read_b128, which is free). Softmax: K pre-scaled by
// 64^-0.5*log2e (log2 domain); shuffle-free defer-max; deferred l-sum;
// masked tail tile kt=16.
__global__ __launch_bounds__(256) void k_attn(
    const __hip_bfloat16* __restrict__ Q, const __hip_bfloat16* __restrict__ Kk,
    const __hip_bfloat16* __restrict__ VT, __hip_bfloat16* __restrict__ ao) {
  __shared__ __hip_bfloat16 Kt[2][64 * 64]; // [key-row][d] swizzled, 8KB/buf
  __shared__ __hip_bfloat16 Vt[2][64 * 64]; // [d-row][key] swizzled, 8KB/buf
  __shared__ __hip_bfloat16 Pl[4][32][72];  // per-wave P tile
  const int tid = threadIdx.x, w = tid >> 6, lane = tid & 63;
  const int l15 = lane & 15, q4 = lane >> 4;
  const int id = blockIdx.x;
  const int xcd = id & 7, sub = id >> 3;   // sub 0..107
  const int hh = sub / 9;                  // head-within-xcd 0..11
  const int bh = xcd * 12 + hh;
  const int qb = (sub - hh * 9) * 128 + w * 32;
  const size_t qbase = (size_t)bh * NTOK * 64;
  const char* Kb = (const char*)(Kk + qbase);
  const char* Vb = (const char*)(VT + (size_t)bh * 64 * NKVPAD);

  // Q fragments (rows clamped; pad rows are discarded at store)
  bf16x8 qa[2][2];
#pragma unroll
  for (int mt = 0; mt < 2; ++mt) {
    int t = qb + mt * 16 + l15;
    if (t > NTOK - 1) t = NTOK - 1;
#pragma unroll
    for (int ks = 0; ks < 2; ++ks)
      qa[mt][ks] = *(const bf16x8*)(Q + qbase + (size_t)t * 64 + ks * 32 + q4 * 8);
  }

  f32x4 accO[2][4] = {};
  float mrun[2][4], lpart[2][4];
#pragma unroll
  for (int mt = 0; mt < 2; ++mt)
#pragma unroll
    for (int j = 0; j < 4; ++j) {
      mrun[mt][j] = -1e30f;
      lpart[mt][j] = 0.0f;
    }

  // stage K/V tile kt into buffer b: 512 16B chunks each, 2 per thread;
  // LDS chunk c = (row = c>>3, phys = c&7) holds source chunk phys^(row&7)
  auto stageKV = [&](int kt, int b) {
    const int kb0 = kt * 64;
#pragma unroll
    for (int i = 0; i < 2; ++i) {
      const int c = i * 256 + tid;
      const int row = c >> 3;
      const int schunk = (c & 7) ^ (row & 7);
      const int srow = min(kb0 + row, NTOK - 1); // clamp; masked in scores
      gl16(Kb + (size_t)srow * 128 + schunk * 16, (char*)&Kt[b][0] + (size_t)c * 16);
      gl16(Vb + (size_t)row * (NKVPAD * 2) + (size_t)kb0 * 2 + schunk * 16,
           (char*)&Vt[b][0] + (size_t)c * 16);
    }
  };

  auto step = [&](int kt, int cur, bool last) {
    const int kb0 = kt * 64;
    // S = Q K^T from LDS (swizzled read), already in log2 domain
    f32x4 s[2][4] = {};
    {
      bf16x8 kfr[2][4];
#pragma unroll
      for (int nt = 0; nt < 4; ++nt) {
        const int row = nt * 16 + l15;
#pragma unroll
        for (int ks = 0; ks < 2; ++ks)
          kfr[ks][nt] = *(const bf16x8*)((const char*)&Kt[cur][0] + row * 128 +
                                         (((ks * 4 + q4) ^ (row & 7)) << 4));
      }
      __builtin_amdgcn_s_setprio(1);
#pragma unroll
      for (int mt = 0; mt < 2; ++mt)
#pragma unroll
        for (int nt = 0; nt < 4; ++nt)
#pragma unroll
          for (int ks = 0; ks < 2; ++ks)
            s[mt][nt] = mfma_bf16(qa[mt][ks], kfr[ks][nt], s[mt][nt]);
      __builtin_amdgcn_s_setprio(0);
    }
    // mask dead key columns on the masked tail tile
    if (last) {
#pragma unroll
      for (int nt = 0; nt < 4; ++nt)
        if (kb0 + nt * 16 + l15 > NTOK - 1) {
#pragma unroll
          for (int mt = 0; mt < 2; ++mt)
#pragma unroll
            for (int j = 0; j < 4; ++j) s[mt][nt][j] = -1e30f;
        }
    }
    // shuffle-free defer-max test: lane-local col max vs mrun+8, __all()
    float smax[2][4];
    bool okl = true;
#pragma unroll
    for (int mt = 0; mt < 2; ++mt)
#pragma unroll
      for (int j = 0; j < 4; ++j) {
        const float a =
            fmaxf(fmaxf(s[mt][0][j], s[mt][1][j]), fmaxf(s[mt][2][j], s[mt][3][j]));
        smax[mt][j] = a;
        okl = okl && (a <= mrun[mt][j] + 8.0f);
      }
    if (!__all((int)okl)) {
      // slow path: true row max via 4-shfl reduce, then rescale state
#pragma unroll
      for (int mt = 0; mt < 2; ++mt)
#pragma unroll
        for (int j = 0; j < 4; ++j) {
          float m0 = smax[mt][j];
#pragma unroll
          for (int off = 1; off < 16; off <<= 1) m0 = fmaxf(m0, __shfl_xor(m0, off));
          const float mnew = fmaxf(mrun[mt][j], m0);
          const float fsc = exp2f(mrun[mt][j] - mnew);
          lpart[mt][j] *= fsc;
          mrun[mt][j] = mnew;
#pragma unroll
          for (int nd = 0; nd < 4; ++nd) accO[mt][nd][j] *= fsc;
        }
    }
    // P = exp2(S - m); per-lane partial sums; stage P to LDS for PV transpose
#pragma unroll
    for (int mt = 0; mt < 2; ++mt)
#pragma unroll
      for (int j = 0; j < 4; ++j) {
        const int row = mt * 16 + q4 * 4 + j;
        float acc = 0.0f;
#pragma unroll
        for (int nt = 0; nt < 4; ++nt) {
          const float p = exp2f(s[mt][nt][j] - mrun[mt][j]);
          acc += p;
          Pl[w][row][nt * 16 + l15] = __float2bfloat16(p);
        }
        lpart[mt][j] += acc;
      }
    // PV; V fragments from swizzled LDS (wave-private Pl ordered by lgkmcnt)
    bf16x8 pa[2][2], vf[2][4];
#pragma unroll
    for (int mt = 0; mt < 2; ++mt)
#pragma unroll
      for (int ks = 0; ks < 2; ++ks)
        pa[mt][ks] = *(const bf16x8*)&Pl[w][mt * 16 + l15][ks * 32 + q4 * 8];
#pragma unroll
    for (int nd = 0; nd < 4; ++nd) {
      const int row = nd * 16 + l15;
#pragma unroll
      for (int ks = 0; ks < 2; ++ks)
        vf[ks][nd] = *(const bf16x8*)((const char*)&Vt[cur][0] + row * 128 +
                                      (((ks * 4 + q4) ^ (row & 7)) << 4));
    }
    __builtin_amdgcn_s_setprio(1);
#pragma unroll
    for (int mt = 0; mt < 2; ++mt)
#pragma unroll
      for (int nd = 0; nd < 4; ++nd)
#pragma unroll
        for (int ks = 0; ks < 2; ++ks)
          accO[mt][nd] = mfma_bf16(pa[mt][ks], vf[ks][nd], accO[mt][nd]);
    __builtin_amdgcn_s_setprio(0);
  };

  stageKV(0, 0);
  __syncthreads();
  for (int kt = 0; kt < 17; ++kt) {
    const int cur = kt & 1;
    if (kt < 16) stageKV(kt + 1, cur ^ 1); // async; flies under compute
    step(kt, cur, kt == 16);
    __syncthreads(); // staging for kt+1 complete; buf[cur] reusable
  }

  // epilogue: one 4-shfl reduce of the deferred l-sum, then store
  const int b = bh / 12, h = bh - (bh / 12) * 12;
#pragma unroll
  for (int mt = 0; mt < 2; ++mt)
#pragma unroll
    for (int j = 0; j < 4; ++j) {
      float sum = lpart[mt][j];
#pragma unroll
      for (int off2 = 1; off2 < 16; off2 <<= 1) sum += __shfl_xor(sum, off2);
      const int t = qb + mt * 16 + q4 * 4 + j;
      if (t > NTOK - 1) continue;
      const float inv = 1.0f / sum;
      const size_t ro = ((size_t)(b * NTOK + t)) * 768 + h * 64;
#pragma unroll
      for (int nd = 0; nd < 4; ++nd) {
        const int d = nd * 16 + l15;
        ao[ro + d] = __float2bfloat16(accO[mt][nd][j] * inv);
      }
    }
}

extern "C" void kernel_launch(void* const* d_in, const int* in_sizes, int n_in,
                              void* d_out, int out_size, void* d_ws, size_t ws_size,
                              hipStream_t stream) {
  const float* x = (const float*)d_in[0];
  const float* sinp = (const float*)d_in[1];
  const float* cosp = (const float*)d_in[2];
  const float* qkvw = (const float*)d_in[3];
  const float* qkvb = (const float*)d_in[4];
  const float* projw = (const float*)d_in[5];
  const float* projb = (const float*)d_in[6];

  char* ws = (char*)d_ws;
  __hip_bfloat16* xhi = (__hip_bfloat16*)(ws + OFF_XHI);
  __hip_bfloat16* xlo = (__hip_bfloat16*)(ws + OFF_XLO);
  __hip_bfloat16* wqhi = (__hip_bfloat16*)(ws + OFF_WQHI);
  __hip_bfloat16* pwhi = (__hip_bfloat16*)(ws + OFF_PWHI);
  __hip_bfloat16* pwlo = (__hip_bfloat16*)(ws + OFF_PWLO);
  __hip_bfloat16* qb = (__hip_bfloat16*)(ws + OFF_Q);
  __hip_bfloat16* kb = (__hip_bfloat16*)(ws + OFF_K);
  __hip_bfloat16* vt = (__hip_bfloat16*)(ws + OFF_VT);
  __hip_bfloat16* ao = (__hip_bfloat16*)(ws + OFF_AO);

  // K0: converts (x gets zero tail to MP rows; qkv_w hi only; proj_w hi+lo)
  {
    int n_src = M * KDIM, n_dst = MP * KDIM;
    k_split<<<(n_dst + 255) / 256, 256, 0, stream>>>(x, xhi, xlo, n_src, n_dst);
    int nw = NQKV * KDIM;
    k_tobf16<<<(nw + 255) / 256, 256, 0, stream>>>(qkvw, wqhi, nw);
    int np = KDIM * KDIM;
    k_split<<<(np + 255) / 256, 256, 0, stream>>>(projw, pwhi, pwlo, np, np);
    int nz = 96 * 64 * (NKVPAD - NTOK);
    k_zero_vt<<<(nz + 255) / 256, 256, 0, stream>>>(vt);
  }
  // K1: QKV GEMM (x split, w single) + bias + RoPE -> q, k(scaled), vT
  // grid 1170 = 18 cols x 65 row-panels, XCD-chunk remapped in-kernel
  k_gemm<0, true, 18><<<dim3(18 * 65), 256, 0, stream>>>(
      xhi, xlo, wqhi, qkvb, sinp, cosp, qb, kb, vt, nullptr);
  // K2: flash attention -> attn_out bf16 (864 = 8 XCD * 12 heads * 9 qblocks)
  k_attn<<<dim3(864), 256, 0, stream>>>(qb, kb, vt, ao);
  // K3: proj GEMM (attn_out single, w split) + bias -> fp32 out
  // grid 390 = 6 cols x 65 row-panels, XCD-chunk remapped in-kernel
  k_gemm<1, false, 6><<<dim3(6 * 65), 256, 0, stream>>>(
      ao, pwlo, pwhi, projb, nullptr, nullptr, nullptr, nullptr, nullptr,
      (float*)d_out);
}

// Round 10
// 237.889 us; speedup vs baseline: 1.2330x; 1.0683x over previous
//
#include <hip/hip_runtime.h>
#include <hip/hip_bf16.h>

// ===== Problem constants =====
// B=8, N=1025, C=768, H=12, HD=64
constexpr int NTOK   = 1025;
constexpr int M      = 8 * NTOK;      // 8200 tokens
constexpr int MP     = 8320;          // 65 * 128 padded rows
constexpr int KDIM   = 768;
constexpr int NQKV   = 2304;
constexpr int NKVPAD = 1088;          // 17*64 padded kv length for vT
constexpr float SCALEL2 = 0.125f * 1.44269504f; // 64^-0.5 * log2(e), folded into K

using bf16x8 = __attribute__((ext_vector_type(8))) short;
using f32x4  = __attribute__((ext_vector_type(4))) float;

__device__ __forceinline__ f32x4 mfma_bf16(bf16x8 a, bf16x8 b, f32x4 c) {
  return __builtin_amdgcn_mfma_f32_16x16x32_bf16(a, b, c, 0, 0, 0);
}

__device__ __forceinline__ void gl16(const void* g, void* l) {
  __builtin_amdgcn_global_load_lds(
      (const __attribute__((address_space(1))) void*)g,
      (__attribute__((address_space(3))) void*)l, 16, 0, 0);
}

// ===== Workspace layout (bytes), all 256-aligned =====
constexpr size_t SZ_X     = (size_t)MP * KDIM * 2;        // 12,779,520
constexpr size_t SZ_WQ    = (size_t)NQKV * KDIM * 2;      // 3,538,944
constexpr size_t SZ_PW    = (size_t)KDIM * KDIM * 2;      // 1,179,648
constexpr size_t SZ_QK    = (size_t)96 * NTOK * 64 * 2;   // 12,595,200
constexpr size_t SZ_VT    = (size_t)96 * 64 * NKVPAD * 2; // 13,369,344
constexpr size_t OFF_XHI  = 0;
constexpr size_t OFF_XLO  = OFF_XHI + SZ_X;   // unused since R10 (1-term QKV)
constexpr size_t OFF_WQHI = OFF_XLO + SZ_X;
constexpr size_t OFF_PWHI = OFF_WQHI + SZ_WQ;
constexpr size_t OFF_PWLO = OFF_PWHI + SZ_PW;
constexpr size_t OFF_Q    = OFF_PWLO + SZ_PW;
constexpr size_t OFF_K    = OFF_Q + SZ_QK;
constexpr size_t OFF_VT   = OFF_K + SZ_QK;
constexpr size_t OFF_AO   = OFF_VT + SZ_VT;
// total ~83 MB

// ===== K0a: fp32 -> (hi,lo) bf16 split =====
__global__ void k_split(const float* __restrict__ src, __hip_bfloat16* __restrict__ hi,
                        __hip_bfloat16* __restrict__ lo, int n_src, int n_dst) {
  int i = blockIdx.x * 256 + threadIdx.x;
  if (i >= n_dst) return;
  float v = (i < n_src) ? src[i] : 0.0f;
  __hip_bfloat16 h = __float2bfloat16(v);
  hi[i] = h;
  lo[i] = __float2bfloat16(v - __bfloat162float(h));
}

// K0b: fp32 -> bf16 with zero tail
__global__ void k_tobf16(const float* __restrict__ src, __hip_bfloat16* __restrict__ dst,
                         int n_src, int n_dst) {
  int i = blockIdx.x * 256 + threadIdx.x;
  if (i >= n_dst) return;
  dst[i] = __float2bfloat16((i < n_src) ? src[i] : 0.0f);
}

// zero vT pad columns (keys 1025..1087) so PV MFMA never sees NaN garbage
__global__ void k_zero_vt(__hip_bfloat16* __restrict__ vt) {
  int i = blockIdx.x * 256 + threadIdx.x;
  constexpr int NPADC = NKVPAD - NTOK; // 63
  if (i >= 96 * 64 * NPADC) return;
  int r = i / NPADC;
  int c = NTOK + (i - r * NPADC);
  vt[(size_t)r * NKVPAD + c] = __float2bfloat16(0.0f);
}

// ===== GEMM core: 128x128 tile, BK=32, swizzled LDS =====
// NT=2: single term acc = A*B (QKV: q/k/v are bf16-stored anyway; the x_lo
//       correction was below the store-rounding floor). 32KB LDS -> up to 5
//       blocks/CU co-resident for latency hiding.
// NT=3: acc = A*Bh + A*Bl (proj keeps the weight split; Asec = B_lo, nBase).
// 1D grid + bijective XCD-chunk remap (T1/m204): each XCD owns ~nwg/8
// CONSECUTIVE logical tiles (x-fastest) so each A row-panel is fetched by
// exactly one XCD's L2.
// 2-phase double-buffered staging: stage(t+1) issued BEFORE compute(t);
// single __syncthreads per step (T3 minimal recipe).
// LDS swizzle (conflict-free ds_read_b128 with linear global_load_lds dest):
//   chunk c (16B) holds global (row=c>>2, slot=(c&3)^((row>>1)&3)) of the tile;
//   4-lane groups still fetch the same contiguous 64B from global (coalesced).
// EPI=0: QKV -> bias + RoPE -> q,k ([bh][t][d] bf16; K pre-scaled by SCALEL2)
//        and vT ([bh][d][t_pad] bf16)
// EPI=1: proj -> bias -> fp32 d_out
template <int EPI, int NT, int NBX>
__global__ __launch_bounds__(256) void k_gemm(
    const __hip_bfloat16* __restrict__ Ahi, const __hip_bfloat16* __restrict__ Asec,
    const __hip_bfloat16* __restrict__ Bhi, const float* __restrict__ bias,
    const float* __restrict__ sinp, const float* __restrict__ cosp,
    __hip_bfloat16* __restrict__ o_q, __hip_bfloat16* __restrict__ o_k,
    __hip_bfloat16* __restrict__ o_vt, float* __restrict__ o_f32) {
  const int tid = threadIdx.x;
  const int w = tid >> 6, lane = tid & 63;
  const int wm = w >> 1, wn = w & 1;
  const int l15 = lane & 15, q4 = lane >> 4;

  // bijective XCD-chunk remap (nwg may not divide by 8)
  const int nwg = gridDim.x;
  const int orig = blockIdx.x;
  const int qc = nwg >> 3, rc = nwg & 7;
  const int xcd = orig & 7, o8 = orig >> 3;
  const int wg =
      (xcd < rc ? xcd * (qc + 1) : rc * (qc + 1) + (xcd - rc) * qc) + o8;
  const int bx = wg % NBX, by = wg / NBX;
  const int mBase = by * 128, nBase = bx * 128;

  __shared__ __hip_bfloat16 sm[2][NT * 4096]; // 2 bufs x NT [128][32] tiles
  constexpr int OFFB = (NT - 1) * 8192;       // byte offset of B_hi tile

  const char* p0 = (const char*)Ahi + (size_t)mBase * (KDIM * 2);
  const char* p1 = (const char*)Asec + (size_t)nBase * (KDIM * 2); // NT==3 only
  const char* p2 = (const char*)Bhi + (size_t)nBase * (KDIM * 2);

  const int slog = ((tid & 3) ^ ((tid >> 3) & 3)) << 4; // staged slot byte offset
  const int ph = ((q4 ^ ((l15 >> 1) & 3)) << 4);        // fragment slot byte offset

  auto stage = [&](int kt, int buf) {
    const int kofs = kt * 64; // bytes into each row
    char* base = (char*)sm[buf];
#pragma unroll
    for (int i = 0; i < 2; ++i) {
      const int c = i * 256 + tid; // 16B chunk index, 512 per tile
      const size_t rb = (size_t)(i * 64 + (tid >> 2)) * (KDIM * 2) + slog + kofs;
      gl16(p0 + rb, base + (size_t)c * 16);
      if (NT == 3) gl16(p1 + rb, base + 8192 + (size_t)c * 16);
      gl16(p2 + rb, base + OFFB + (size_t)c * 16);
    }
  };

  f32x4 acc[4][4] = {};

  stage(0, 0);
  __syncthreads();

  constexpr int NKT = KDIM / 32; // 24
  for (int kt = 0; kt < NKT; ++kt) {
    const int cur = kt & 1;
    if (kt + 1 < NKT) stage(kt + 1, cur ^ 1); // async; flies under compute
    char* s0 = (char*)sm[cur];
    char* s1 = s0 + 8192;
    char* s2 = s0 + OFFB;
    bf16x8 a0[4], b0[4], b1[4];
#pragma unroll
    for (int mt = 0; mt < 4; ++mt) {
      const int r = wm * 64 + mt * 16 + l15;
      a0[mt] = *(const bf16x8*)(s0 + r * 64 + ph);
    }
#pragma unroll
    for (int nt = 0; nt < 4; ++nt) {
      const int r = wn * 64 + nt * 16 + l15;
      b0[nt] = *(const bf16x8*)(s2 + r * 64 + ph);
      if (NT == 3) b1[nt] = *(const bf16x8*)(s1 + r * 64 + ph);
    }
    __builtin_amdgcn_s_setprio(1);
#pragma unroll
    for (int mt = 0; mt < 4; ++mt)
#pragma unroll
      for (int nt = 0; nt < 4; ++nt) {
        acc[mt][nt] = mfma_bf16(a0[mt], b0[nt], acc[mt][nt]);
        if (NT == 3) acc[mt][nt] = mfma_bf16(a0[mt], b1[nt], acc[mt][nt]);
      }
    __builtin_amdgcn_s_setprio(0);
    __syncthreads(); // drains vmcnt -> buf[cur^1] complete; buf[cur] reusable
  }

  // epilogue; C layout: col = lane&15, row = 4*(lane>>4)+j
#pragma unroll
  for (int mt = 0; mt < 4; ++mt)
#pragma unroll
    for (int j = 0; j < 4; ++j) {
      const int gm = mBase + wm * 64 + mt * 16 + q4 * 4 + j;
      if (gm >= M) continue;
      if (EPI == 0) {
        const int b = gm / NTOK;
        const int t = gm - b * NTOK;
#pragma unroll
        for (int nt = 0; nt < 4; ++nt) {
          const int gc = nBase + wn * 64 + nt * 16 + l15;
          float v = acc[mt][nt][j] + bias[gc];
          const int three = gc / 768;
          const int hd = gc - three * 768;
          const int h = hd >> 6, d = hd & 63;
          const int bh = b * 12 + h;
          if (three == 2) {
            o_vt[((size_t)bh * 64 + d) * NKVPAD + t] = __float2bfloat16(v);
          } else {
            if (t > 0) {
              const float pv = acc[mt][nt ^ 2][j] + bias[gc ^ 32];
              const int so = (t - 1) * 64 + d;
              v = v * cosp[so] + ((d < 32) ? -pv : pv) * sinp[so];
            }
            if (three == 0)
              o_q[((size_t)bh * NTOK + t) * 64 + d] = __float2bfloat16(v);
            else  // K: fold softmax scale * log2(e) here (bf16 rel-err scale-invariant)
              o_k[((size_t)bh * NTOK + t) * 64 + d] = __float2bfloat16(v * SCALEL2);
          }
        }
      } else {
#pragma unroll
        for (int nt = 0; nt < 4; ++nt) {
          const int gc = nBase + wn * 64 + nt * 16 + l15;
          o_f32[(size_t)gm * 768 + gc] = acc[mt][nt][j] + bias[gc];
        }
      }
    }
}

// ===== K2: flash attention, 4 waves x 32 q-rows, KV tiles of 64 =====
// Grid: 864 = 8 XCD chunks * 12 heads * 9 q-blocks. K/V tiles are staged in
// LDS once per BLOCK (shared by the 4 waves), double-buffered, via
// global_load_lds with chunk-XOR swizzle (linear LDS dest + pre-swizzled
// global source chunk^=(row&7); read side applies the same XOR -> <=2-way
// bank aliasing on ds_read_b128, which is free). Softmax: K pre-scaled by
// 64^-0.5*log2e (log2 domain); shuffle-free defer-max; deferred l-sum;
// masked tail tile kt=16.
__global__ __launch_bounds__(256) void k_attn(
    const __hip_bfloat16* __restrict__ Q, const __hip_bfloat16* __restrict__ Kk,
    const __hip_bfloat16* __restrict__ VT, __hip_bfloat16* __restrict__ ao) {
  __shared__ __hip_bfloat16 Kt[2][64 * 64]; // [key-row][d] swizzled, 8KB/buf
  __shared__ __hip_bfloat16 Vt[2][64 * 64]; // [d-row][key] swizzled, 8KB/buf
  __shared__ __hip_bfloat16 Pl[4][32][72];  // per-wave P tile
  const int tid = threadIdx.x, w = tid >> 6, lane = tid & 63;
  const int l15 = lane & 15, q4 = lane >> 4;
  const int id = blockIdx.x;
  const int xcd = id & 7, sub = id >> 3;   // sub 0..107
  const int hh = sub / 9;                  // head-within-xcd 0..11
  const int bh = xcd * 12 + hh;
  const int qb = (sub - hh * 9) * 128 + w * 32;
  const size_t qbase = (size_t)bh * NTOK * 64;
  const char* Kb = (const char*)(Kk + qbase);
  const char* Vb = (const char*)(VT + (size_t)bh * 64 * NKVPAD);

  // Q fragments (rows clamped; pad rows are discarded at store)
  bf16x8 qa[2][2];
#pragma unroll
  for (int mt = 0; mt < 2; ++mt) {
    int t = qb + mt * 16 + l15;
    if (t > NTOK - 1) t = NTOK - 1;
#pragma unroll
    for (int ks = 0; ks < 2; ++ks)
      qa[mt][ks] = *(const bf16x8*)(Q + qbase + (size_t)t * 64 + ks * 32 + q4 * 8);
  }

  f32x4 accO[2][4] = {};
  float mrun[2][4], lpart[2][4];
#pragma unroll
  for (int mt = 0; mt < 2; ++mt)
#pragma unroll
    for (int j = 0; j < 4; ++j) {
      mrun[mt][j] = -1e30f;
      lpart[mt][j] = 0.0f;
    }

  // stage K/V tile kt into buffer b: 512 16B chunks each, 2 per thread;
  // LDS chunk c = (row = c>>3, phys = c&7) holds source chunk phys^(row&7)
  auto stageKV = [&](int kt, int b) {
    const int kb0 = kt * 64;
#pragma unroll
    for (int i = 0; i < 2; ++i) {
      const int c = i * 256 + tid;
      const int row = c >> 3;
      const int schunk = (c & 7) ^ (row & 7);
      const int srow = min(kb0 + row, NTOK - 1); // clamp; masked in scores
      gl16(Kb + (size_t)srow * 128 + schunk * 16, (char*)&Kt[b][0] + (size_t)c * 16);
      gl16(Vb + (size_t)row * (NKVPAD * 2) + (size_t)kb0 * 2 + schunk * 16,
           (char*)&Vt[b][0] + (size_t)c * 16);
    }
  };

  auto step = [&](int kt, int cur, bool last) {
    const int kb0 = kt * 64;
    // S = Q K^T from LDS (swizzled read), already in log2 domain
    f32x4 s[2][4] = {};
    {
      bf16x8 kfr[2][4];
#pragma unroll
      for (int nt = 0; nt < 4; ++nt) {
        const int row = nt * 16 + l15;
#pragma unroll
        for (int ks = 0; ks < 2; ++ks)
          kfr[ks][nt] = *(const bf16x8*)((const char*)&Kt[cur][0] + row * 128 +
                                         (((ks * 4 + q4) ^ (row & 7)) << 4));
      }
      __builtin_amdgcn_s_setprio(1);
#pragma unroll
      for (int mt = 0; mt < 2; ++mt)
#pragma unroll
        for (int nt = 0; nt < 4; ++nt)
#pragma unroll
          for (int ks = 0; ks < 2; ++ks)
            s[mt][nt] = mfma_bf16(qa[mt][ks], kfr[ks][nt], s[mt][nt]);
      __builtin_amdgcn_s_setprio(0);
    }
    // mask dead key columns on the masked tail tile
    if (last) {
#pragma unroll
      for (int nt = 0; nt < 4; ++nt)
        if (kb0 + nt * 16 + l15 > NTOK - 1) {
#pragma unroll
          for (int mt = 0; mt < 2; ++mt)
#pragma unroll
            for (int j = 0; j < 4; ++j) s[mt][nt][j] = -1e30f;
        }
    }
    // shuffle-free defer-max test: lane-local col max vs mrun+8, __all()
    float smax[2][4];
    bool okl = true;
#pragma unroll
    for (int mt = 0; mt < 2; ++mt)
#pragma unroll
      for (int j = 0; j < 4; ++j) {
        const float a =
            fmaxf(fmaxf(s[mt][0][j], s[mt][1][j]), fmaxf(s[mt][2][j], s[mt][3][j]));
        smax[mt][j] = a;
        okl = okl && (a <= mrun[mt][j] + 8.0f);
      }
    if (!__all((int)okl)) {
      // slow path: true row max via 4-shfl reduce, then rescale state
#pragma unroll
      for (int mt = 0; mt < 2; ++mt)
#pragma unroll
        for (int j = 0; j < 4; ++j) {
          float m0 = smax[mt][j];
#pragma unroll
          for (int off = 1; off < 16; off <<= 1) m0 = fmaxf(m0, __shfl_xor(m0, off));
          const float mnew = fmaxf(mrun[mt][j], m0);
          const float fsc = exp2f(mrun[mt][j] - mnew);
          lpart[mt][j] *= fsc;
          mrun[mt][j] = mnew;
#pragma unroll
          for (int nd = 0; nd < 4; ++nd) accO[mt][nd][j] *= fsc;
        }
    }
    // P = exp2(S - m); per-lane partial sums; stage P to LDS for PV transpose
#pragma unroll
    for (int mt = 0; mt < 2; ++mt)
#pragma unroll
      for (int j = 0; j < 4; ++j) {
        const int row = mt * 16 + q4 * 4 + j;
        float acc = 0.0f;
#pragma unroll
        for (int nt = 0; nt < 4; ++nt) {
          const float p = exp2f(s[mt][nt][j] - mrun[mt][j]);
          acc += p;
          Pl[w][row][nt * 16 + l15] = __float2bfloat16(p);
        }
        lpart[mt][j] += acc;
      }
    // PV; V fragments from swizzled LDS (wave-private Pl ordered by lgkmcnt)
    bf16x8 pa[2][2], vf[2][4];
#pragma unroll
    for (int mt = 0; mt < 2; ++mt)
#pragma unroll
      for (int ks = 0; ks < 2; ++ks)
        pa[mt][ks] = *(const bf16x8*)&Pl[w][mt * 16 + l15][ks * 32 + q4 * 8];
#pragma unroll
    for (int nd = 0; nd < 4; ++nd) {
      const int row = nd * 16 + l15;
#pragma unroll
      for (int ks = 0; ks < 2; ++ks)
        vf[ks][nd] = *(const bf16x8*)((const char*)&Vt[cur][0] + row * 128 +
                                      (((ks * 4 + q4) ^ (row & 7)) << 4));
    }
    __builtin_amdgcn_s_setprio(1);
#pragma unroll
    for (int mt = 0; mt < 2; ++mt)
#pragma unroll
      for (int nd = 0; nd < 4; ++nd)
#pragma unroll
        for (int ks = 0; ks < 2; ++ks)
          accO[mt][nd] = mfma_bf16(pa[mt][ks], vf[ks][nd], accO[mt][nd]);
    __builtin_amdgcn_s_setprio(0);
  };

  stageKV(0, 0);
  __syncthreads();
  for (int kt = 0; kt < 17; ++kt) {
    const int cur = kt & 1;
    if (kt < 16) stageKV(kt + 1, cur ^ 1); // async; flies under compute
    step(kt, cur, kt == 16);
    __syncthreads(); // staging for kt+1 complete; buf[cur] reusable
  }

  // epilogue: one 4-shfl reduce of the deferred l-sum, then store
  const int b = bh / 12, h = bh - (bh / 12) * 12;
#pragma unroll
  for (int mt = 0; mt < 2; ++mt)
#pragma unroll
    for (int j = 0; j < 4; ++j) {
      float sum = lpart[mt][j];
#pragma unroll
      for (int off2 = 1; off2 < 16; off2 <<= 1) sum += __shfl_xor(sum, off2);
      const int t = qb + mt * 16 + q4 * 4 + j;
      if (t > NTOK - 1) continue;
      const float inv = 1.0f / sum;
      const size_t ro = ((size_t)(b * NTOK + t)) * 768 + h * 64;
#pragma unroll
      for (int nd = 0; nd < 4; ++nd) {
        const int d = nd * 16 + l15;
        ao[ro + d] = __float2bfloat16(accO[mt][nd][j] * inv);
      }
    }
}

extern "C" void kernel_launch(void* const* d_in, const int* in_sizes, int n_in,
                              void* d_out, int out_size, void* d_ws, size_t ws_size,
                              hipStream_t stream) {
  const float* x = (const float*)d_in[0];
  const float* sinp = (const float*)d_in[1];
  const float* cosp = (const float*)d_in[2];
  const float* qkvw = (const float*)d_in[3];
  const float* qkvb = (const float*)d_in[4];
  const float* projw = (const float*)d_in[5];
  const float* projb = (const float*)d_in[6];

  char* ws = (char*)d_ws;
  __hip_bfloat16* xhi = (__hip_bfloat16*)(ws + OFF_XHI);
  __hip_bfloat16* wqhi = (__hip_bfloat16*)(ws + OFF_WQHI);
  __hip_bfloat16* pwhi = (__hip_bfloat16*)(ws + OFF_PWHI);
  __hip_bfloat16* pwlo = (__hip_bfloat16*)(ws + OFF_PWLO);
  __hip_bfloat16* qb = (__hip_bfloat16*)(ws + OFF_Q);
  __hip_bfloat16* kb = (__hip_bfloat16*)(ws + OFF_K);
  __hip_bfloat16* vt = (__hip_bfloat16*)(ws + OFF_VT);
  __hip_bfloat16* ao = (__hip_bfloat16*)(ws + OFF_AO);

  // K0: converts (x: plain bf16 cast with zero tail; qkv_w hi; proj_w hi+lo)
  {
    int n_src = M * KDIM, n_dst = MP * KDIM;
    k_tobf16<<<(n_dst + 255) / 256, 256, 0, stream>>>(x, xhi, n_src, n_dst);
    int nw = NQKV * KDIM;
    k_tobf16<<<(nw + 255) / 256, 256, 0, stream>>>(qkvw, wqhi, nw, nw);
    int np = KDIM * KDIM;
    k_split<<<(np + 255) / 256, 256, 0, stream>>>(projw, pwhi, pwlo, np, np);
    int nz = 96 * 64 * (NKVPAD - NTOK);
    k_zero_vt<<<(nz + 255) / 256, 256, 0, stream>>>(vt);
  }
  // K1: QKV GEMM (single term) + bias + RoPE -> q, k(scaled), vT
  // grid 1170 = 18 cols x 65 row-panels, XCD-chunk remapped in-kernel
  k_gemm<0, 2, 18><<<dim3(18 * 65), 256, 0, stream>>>(
      xhi, xhi, wqhi, qkvb, sinp, cosp, qb, kb, vt, nullptr);
  // K2: flash attention -> attn_out bf16 (864 = 8 XCD * 12 heads * 9 qblocks)
  k_attn<<<dim3(864), 256, 0, stream>>>(qb, kb, vt, ao);
  // K3: proj GEMM (attn_out single, w split) + bias -> fp32 out
  // grid 390 = 6 cols x 65 row-panels, XCD-chunk remapped in-kernel
  k_gemm<1, 3, 6><<<dim3(6 * 65), 256, 0, stream>>>(
      ao, pwlo, pwhi, projb, nullptr, nullptr, nullptr, nullptr, nullptr,
      (float*)d_out);
}

// Round 11
// 224.810 us; speedup vs baseline: 1.3047x; 1.0582x over previous
//
#include <hip/hip_runtime.h>
#include <hip/hip_bf16.h>

// ===== Problem constants =====
// B=8, N=1025, C=768, H=12, HD=64
constexpr int NTOK   = 1025;
constexpr int M      = 8 * NTOK;      // 8200 tokens
constexpr int MP     = 8320;          // 65 * 128 padded rows
constexpr int KDIM   = 768;
constexpr int NQKV   = 2304;
constexpr int NKVPAD = 1088;          // 17*64 padded kv length for vT
constexpr float SCALEL2 = 0.125f * 1.44269504f; // 64^-0.5 * log2(e), folded into K

using bf16x8 = __attribute__((ext_vector_type(8))) short;
using f32x4  = __attribute__((ext_vector_type(4))) float;

__device__ __forceinline__ f32x4 mfma_bf16(bf16x8 a, bf16x8 b, f32x4 c) {
  return __builtin_amdgcn_mfma_f32_16x16x32_bf16(a, b, c, 0, 0, 0);
}

__device__ __forceinline__ void gl16(const void* g, void* l) {
  __builtin_amdgcn_global_load_lds(
      (const __attribute__((address_space(1))) void*)g,
      (__attribute__((address_space(3))) void*)l, 16, 0, 0);
}

// raw 2^x (args bounded by defer-max <= 8; -1e30 masks flush to 0) — the
// OCML exp2 wrapper costs ~6 VALU ops; the instruction is 1 trans op.
__device__ __forceinline__ float exp2_raw(float x) {
  float r;
  asm("v_exp_f32 %0, %1" : "=v"(r) : "v"(x));
  return r;
}
// hardware-RNE f32->bf16 (1 op vs ~5-op software RNE in __float2bfloat16)
__device__ __forceinline__ __hip_bfloat16 cvt_bf16_raw(float x) {
  unsigned u;
  asm("v_cvt_pk_bf16_f32 %0, %1, %2" : "=v"(u) : "v"(x), "v"(x));
  union { unsigned short s; __hip_bfloat16 b; } c;
  c.s = (unsigned short)(u & 0xffffu);
  return c.b;
}

// ===== Workspace layout (bytes), all 256-aligned =====
constexpr size_t SZ_X     = (size_t)MP * KDIM * 2;        // 12,779,520
constexpr size_t SZ_WQ    = (size_t)NQKV * KDIM * 2;      // 3,538,944
constexpr size_t SZ_PW    = (size_t)KDIM * KDIM * 2;      // 1,179,648
constexpr size_t SZ_QK    = (size_t)96 * NTOK * 64 * 2;   // 12,595,200
constexpr size_t SZ_VT    = (size_t)96 * 64 * NKVPAD * 2; // 13,369,344
constexpr size_t OFF_XHI  = 0;
constexpr size_t OFF_XLO  = OFF_XHI + SZ_X;   // unused since R10 (1-term QKV)
constexpr size_t OFF_WQHI = OFF_XLO + SZ_X;
constexpr size_t OFF_PWHI = OFF_WQHI + SZ_WQ;
constexpr size_t OFF_PWLO = OFF_PWHI + SZ_PW;
constexpr size_t OFF_Q    = OFF_PWLO + SZ_PW;
constexpr size_t OFF_K    = OFF_Q + SZ_QK;
constexpr size_t OFF_VT   = OFF_K + SZ_QK;
constexpr size_t OFF_AO   = OFF_VT + SZ_VT;
// total ~83 MB

// ===== K0a: fp32 -> (hi,lo) bf16 split =====
__global__ void k_split(const float* __restrict__ src, __hip_bfloat16* __restrict__ hi,
                        __hip_bfloat16* __restrict__ lo, int n_src, int n_dst) {
  int i = blockIdx.x * 256 + threadIdx.x;
  if (i >= n_dst) return;
  float v = (i < n_src) ? src[i] : 0.0f;
  __hip_bfloat16 h = __float2bfloat16(v);
  hi[i] = h;
  lo[i] = __float2bfloat16(v - __bfloat162float(h));
}

// K0b: fp32 -> bf16 with zero tail
__global__ void k_tobf16(const float* __restrict__ src, __hip_bfloat16* __restrict__ dst,
                         int n_src, int n_dst) {
  int i = blockIdx.x * 256 + threadIdx.x;
  if (i >= n_dst) return;
  dst[i] = __float2bfloat16((i < n_src) ? src[i] : 0.0f);
}

// zero vT pad columns (keys 1025..1087) so PV MFMA never sees NaN garbage
__global__ void k_zero_vt(__hip_bfloat16* __restrict__ vt) {
  int i = blockIdx.x * 256 + threadIdx.x;
  constexpr int NPADC = NKVPAD - NTOK; // 63
  if (i >= 96 * 64 * NPADC) return;
  int r = i / NPADC;
  int c = NTOK + (i - r * NPADC);
  vt[(size_t)r * NKVPAD + c] = __float2bfloat16(0.0f);
}

// ===== GEMM core: 128x128 tile, BK=32, swizzled LDS =====
// NT=2: single term acc = A*B (QKV). NT=3: acc = A*Bh + A*Bl (proj w-split).
// 1D grid + bijective XCD-chunk remap (T1/m204). 2-phase double-buffered
// staging (T3 minimal recipe). LDS chunk-XOR swizzle -> conflict-free
// ds_read_b128 with linear global_load_lds dest.
// EPI=0: QKV -> bias + RoPE -> q,k ([bh][t][d] bf16; K pre-scaled by SCALEL2)
//        and vT ([bh][d][t_pad] bf16)
// EPI=1: proj -> bias -> fp32 d_out
template <int EPI, int NT, int NBX>
__global__ __launch_bounds__(256) void k_gemm(
    const __hip_bfloat16* __restrict__ Ahi, const __hip_bfloat16* __restrict__ Asec,
    const __hip_bfloat16* __restrict__ Bhi, const float* __restrict__ bias,
    const float* __restrict__ sinp, const float* __restrict__ cosp,
    __hip_bfloat16* __restrict__ o_q, __hip_bfloat16* __restrict__ o_k,
    __hip_bfloat16* __restrict__ o_vt, float* __restrict__ o_f32) {
  const int tid = threadIdx.x;
  const int w = tid >> 6, lane = tid & 63;
  const int wm = w >> 1, wn = w & 1;
  const int l15 = lane & 15, q4 = lane >> 4;

  // bijective XCD-chunk remap (nwg may not divide by 8)
  const int nwg = gridDim.x;
  const int orig = blockIdx.x;
  const int qc = nwg >> 3, rc = nwg & 7;
  const int xcd = orig & 7, o8 = orig >> 3;
  const int wg =
      (xcd < rc ? xcd * (qc + 1) : rc * (qc + 1) + (xcd - rc) * qc) + o8;
  const int bx = wg % NBX, by = wg / NBX;
  const int mBase = by * 128, nBase = bx * 128;

  __shared__ __hip_bfloat16 sm[2][NT * 4096]; // 2 bufs x NT [128][32] tiles
  constexpr int OFFB = (NT - 1) * 8192;       // byte offset of B_hi tile

  const char* p0 = (const char*)Ahi + (size_t)mBase * (KDIM * 2);
  const char* p1 = (const char*)Asec + (size_t)nBase * (KDIM * 2); // NT==3 only
  const char* p2 = (const char*)Bhi + (size_t)nBase * (KDIM * 2);

  const int slog = ((tid & 3) ^ ((tid >> 3) & 3)) << 4; // staged slot byte offset
  const int ph = ((q4 ^ ((l15 >> 1) & 3)) << 4);        // fragment slot byte offset

  auto stage = [&](int kt, int buf) {
    const int kofs = kt * 64; // bytes into each row
    char* base = (char*)sm[buf];
#pragma unroll
    for (int i = 0; i < 2; ++i) {
      const int c = i * 256 + tid; // 16B chunk index, 512 per tile
      const size_t rb = (size_t)(i * 64 + (tid >> 2)) * (KDIM * 2) + slog + kofs;
      gl16(p0 + rb, base + (size_t)c * 16);
      if (NT == 3) gl16(p1 + rb, base + 8192 + (size_t)c * 16);
      gl16(p2 + rb, base + OFFB + (size_t)c * 16);
    }
  };

  f32x4 acc[4][4] = {};

  stage(0, 0);
  __syncthreads();

  constexpr int NKT = KDIM / 32; // 24
  for (int kt = 0; kt < NKT; ++kt) {
    const int cur = kt & 1;
    if (kt + 1 < NKT) stage(kt + 1, cur ^ 1); // async; flies under compute
    char* s0 = (char*)sm[cur];
    char* s1 = s0 + 8192;
    char* s2 = s0 + OFFB;
    bf16x8 a0[4], b0[4], b1[4];
#pragma unroll
    for (int mt = 0; mt < 4; ++mt) {
      const int r = wm * 64 + mt * 16 + l15;
      a0[mt] = *(const bf16x8*)(s0 + r * 64 + ph);
    }
#pragma unroll
    for (int nt = 0; nt < 4; ++nt) {
      const int r = wn * 64 + nt * 16 + l15;
      b0[nt] = *(const bf16x8*)(s2 + r * 64 + ph);
      if (NT == 3) b1[nt] = *(const bf16x8*)(s1 + r * 64 + ph);
    }
    __builtin_amdgcn_s_setprio(1);
#pragma unroll
    for (int mt = 0; mt < 4; ++mt)
#pragma unroll
      for (int nt = 0; nt < 4; ++nt) {
        acc[mt][nt] = mfma_bf16(a0[mt], b0[nt], acc[mt][nt]);
        if (NT == 3) acc[mt][nt] = mfma_bf16(a0[mt], b1[nt], acc[mt][nt]);
      }
    __builtin_amdgcn_s_setprio(0);
    __syncthreads(); // drains vmcnt -> buf[cur^1] complete; buf[cur] reusable
  }

  // epilogue; C layout: col = lane&15, row = 4*(lane>>4)+j
#pragma unroll
  for (int mt = 0; mt < 4; ++mt)
#pragma unroll
    for (int j = 0; j < 4; ++j) {
      const int gm = mBase + wm * 64 + mt * 16 + q4 * 4 + j;
      if (gm >= M) continue;
      if (EPI == 0) {
        const int b = gm / NTOK;
        const int t = gm - b * NTOK;
#pragma unroll
        for (int nt = 0; nt < 4; ++nt) {
          const int gc = nBase + wn * 64 + nt * 16 + l15;
          float v = acc[mt][nt][j] + bias[gc];
          const int three = gc / 768;
          const int hd = gc - three * 768;
          const int h = hd >> 6, d = hd & 63;
          const int bh = b * 12 + h;
          if (three == 2) {
            o_vt[((size_t)bh * 64 + d) * NKVPAD + t] = __float2bfloat16(v);
          } else {
            if (t > 0) {
              const float pv = acc[mt][nt ^ 2][j] + bias[gc ^ 32];
              const int so = (t - 1) * 64 + d;
              v = v * cosp[so] + ((d < 32) ? -pv : pv) * sinp[so];
            }
            if (three == 0)
              o_q[((size_t)bh * NTOK + t) * 64 + d] = __float2bfloat16(v);
            else  // K: fold softmax scale * log2(e) here (bf16 rel-err scale-invariant)
              o_k[((size_t)bh * NTOK + t) * 64 + d] = __float2bfloat16(v * SCALEL2);
          }
        }
      } else {
#pragma unroll
        for (int nt = 0; nt < 4; ++nt) {
          const int gc = nBase + wn * 64 + nt * 16 + l15;
          o_f32[(size_t)gm * 768 + gc] = acc[mt][nt][j] + bias[gc];
        }
      }
    }
}

// ===== K2: flash attention, 4 waves x 32 q-rows, KV tiles of 64 =====
// Grid: 864 = 8 XCD chunks * 12 heads * 9 q-blocks. K/V staged in LDS once
// per BLOCK, double-buffered, chunk-XOR swizzled (free <=2-way aliasing).
// Softmax: K pre-scaled (log2 domain); shuffle-free defer-max; deferred
// l-sum; masked tail tile kt=16. VALU-lean: raw v_exp_f32 / v_cvt_pk_bf16
// (1 op vs 5-6 op library sequences) and ALL swizzled LDS offsets hoisted
// out of the K-loop (per step only +kb0*stride scalar adds remain).
__global__ __launch_bounds__(256) void k_attn(
    const __hip_bfloat16* __restrict__ Q, const __hip_bfloat16* __restrict__ Kk,
    const __hip_bfloat16* __restrict__ VT, __hip_bfloat16* __restrict__ ao) {
  __shared__ __hip_bfloat16 Kt[2][64 * 64]; // [key-row][d] swizzled, 8KB/buf
  __shared__ __hip_bfloat16 Vt[2][64 * 64]; // [d-row][key] swizzled, 8KB/buf
  __shared__ __hip_bfloat16 Pl[4][32][72];  // per-wave P tile
  const int tid = threadIdx.x, w = tid >> 6, lane = tid & 63;
  const int l15 = lane & 15, q4 = lane >> 4;
  const int id = blockIdx.x;
  const int xcd = id & 7, sub = id >> 3;   // sub 0..107
  const int hh = sub / 9;                  // head-within-xcd 0..11
  const int bh = xcd * 12 + hh;
  const int qb = (sub - hh * 9) * 128 + w * 32;
  const size_t qbase = (size_t)bh * NTOK * 64;
  const char* Kb = (const char*)(Kk + qbase);
  const char* Vb = (const char*)(VT + (size_t)bh * 64 * NKVPAD);

  // ---- hoisted per-lane offsets (constant across the K-loop) ----
  // fragment reads (shared by K and V tiles): row = f*16 + l15
  int frag_off[2][4];
#pragma unroll
  for (int f = 0; f < 4; ++f) {
    const int row = f * 16 + l15;
#pragma unroll
    for (int ks = 0; ks < 2; ++ks)
      frag_off[ks][f] = row * 128 + (((ks * 4 + q4) ^ (row & 7)) << 4);
  }
  // staging: chunk c -> (row, swizzled slot)
  int stRow[2], sch16[2], stK[2], stV[2], ldsOff[2];
#pragma unroll
  for (int i = 0; i < 2; ++i) {
    const int c = i * 256 + tid;
    const int row = c >> 3;
    stRow[i] = row;
    sch16[i] = ((c & 7) ^ (row & 7)) << 4;
    stK[i] = row * 128 + sch16[i];
    stV[i] = row * (NKVPAD * 2) + sch16[i];
    ldsOff[i] = c * 16;
  }
  // P tile byte offsets: writes (per mt,j row; +nt*32 imm) and reads (per mt,ks)
  int pw_off[2][4], pa_off[2][2];
#pragma unroll
  for (int mt = 0; mt < 2; ++mt) {
#pragma unroll
    for (int j = 0; j < 4; ++j)
      pw_off[mt][j] = ((w * 32 + mt * 16 + q4 * 4 + j) * 72 + l15) * 2;
#pragma unroll
    for (int ks = 0; ks < 2; ++ks)
      pa_off[mt][ks] = ((w * 32 + mt * 16 + l15) * 72 + ks * 32 + q4 * 8) * 2;
  }
  char* Plc = (char*)&Pl[0][0][0];

  // Q fragments (rows clamped; pad rows are discarded at store)
  bf16x8 qa[2][2];
#pragma unroll
  for (int mt = 0; mt < 2; ++mt) {
    int t = qb + mt * 16 + l15;
    if (t > NTOK - 1) t = NTOK - 1;
#pragma unroll
    for (int ks = 0; ks < 2; ++ks)
      qa[mt][ks] = *(const bf16x8*)(Q + qbase + (size_t)t * 64 + ks * 32 + q4 * 8);
  }

  f32x4 accO[2][4] = {};
  float mrun[2][4], lpart[2][4];
#pragma unroll
  for (int mt = 0; mt < 2; ++mt)
#pragma unroll
    for (int j = 0; j < 4; ++j) {
      mrun[mt][j] = -1e30f;
      lpart[mt][j] = 0.0f;
    }

  auto stageKV = [&](int kt, int b) {
    const int kb0 = kt * 64;
#pragma unroll
    for (int i = 0; i < 2; ++i) {
      const char* srcK;
      if (kt == 16) { // tail: clamp key rows (masked in scores)
        const int srow = min(kb0 + stRow[i], NTOK - 1);
        srcK = Kb + (size_t)srow * 128 + sch16[i];
      } else {
        srcK = Kb + (size_t)kb0 * 128 + stK[i];
      }
      gl16(srcK, (char*)&Kt[b][0] + ldsOff[i]);
      gl16(Vb + (size_t)kb0 * 2 + stV[i], (char*)&Vt[b][0] + ldsOff[i]);
    }
  };

  auto step = [&](int kt, int cur, bool last) {
    // S = Q K^T from LDS (swizzled read), already in log2 domain
    f32x4 s[2][4] = {};
    {
      const char* Kc = (const char*)&Kt[cur][0];
      bf16x8 kfr[2][4];
#pragma unroll
      for (int nt = 0; nt < 4; ++nt)
#pragma unroll
        for (int ks = 0; ks < 2; ++ks)
          kfr[ks][nt] = *(const bf16x8*)(Kc + frag_off[ks][nt]);
      __builtin_amdgcn_s_setprio(1);
#pragma unroll
      for (int mt = 0; mt < 2; ++mt)
#pragma unroll
        for (int nt = 0; nt < 4; ++nt)
#pragma unroll
          for (int ks = 0; ks < 2; ++ks)
            s[mt][nt] = mfma_bf16(qa[mt][ks], kfr[ks][nt], s[mt][nt]);
      __builtin_amdgcn_s_setprio(0);
    }
    // mask dead key columns on the masked tail tile
    if (last) {
#pragma unroll
      for (int nt = 0; nt < 4; ++nt)
        if (1024 + nt * 16 + l15 > NTOK - 1) {
#pragma unroll
          for (int mt = 0; mt < 2; ++mt)
#pragma unroll
            for (int j = 0; j < 4; ++j) s[mt][nt][j] = -1e30f;
        }
    }
    // shuffle-free defer-max test: lane-local col max vs mrun+8, __all()
    float smax[2][4];
    bool okl = true;
#pragma unroll
    for (int mt = 0; mt < 2; ++mt)
#pragma unroll
      for (int j = 0; j < 4; ++j) {
        const float a =
            fmaxf(fmaxf(s[mt][0][j], s[mt][1][j]), fmaxf(s[mt][2][j], s[mt][3][j]));
        smax[mt][j] = a;
        okl = okl && (a <= mrun[mt][j] + 8.0f);
      }
    if (!__all((int)okl)) {
      // slow path: true row max via 4-shfl reduce, then rescale state
#pragma unroll
      for (int mt = 0; mt < 2; ++mt)
#pragma unroll
        for (int j = 0; j < 4; ++j) {
          float m0 = smax[mt][j];
#pragma unroll
          for (int off = 1; off < 16; off <<= 1) m0 = fmaxf(m0, __shfl_xor(m0, off));
          const float mnew = fmaxf(mrun[mt][j], m0);
          const float fsc = exp2_raw(mrun[mt][j] - mnew);
          lpart[mt][j] *= fsc;
          mrun[mt][j] = mnew;
#pragma unroll
          for (int nd = 0; nd < 4; ++nd) accO[mt][nd][j] *= fsc;
        }
    }
    // P = exp2(S - m); per-lane partial sums; stage P to LDS for PV transpose
#pragma unroll
    for (int mt = 0; mt < 2; ++mt)
#pragma unroll
      for (int j = 0; j < 4; ++j) {
        float acc = 0.0f;
        char* pw = Plc + pw_off[mt][j];
#pragma unroll
        for (int nt = 0; nt < 4; ++nt) {
          const float p = exp2_raw(s[mt][nt][j] - mrun[mt][j]);
          acc += p;
          *(__hip_bfloat16*)(pw + nt * 32) = cvt_bf16_raw(p);
        }
        lpart[mt][j] += acc;
      }
    // PV; V fragments from swizzled LDS (wave-private Pl ordered by lgkmcnt)
    bf16x8 pa[2][2], vf[2][4];
#pragma unroll
    for (int mt = 0; mt < 2; ++mt)
#pragma unroll
      for (int ks = 0; ks < 2; ++ks)
        pa[mt][ks] = *(const bf16x8*)(Plc + pa_off[mt][ks]);
    {
      const char* Vc = (const char*)&Vt[cur][0];
#pragma unroll
      for (int nd = 0; nd < 4; ++nd)
#pragma unroll
        for (int ks = 0; ks < 2; ++ks)
          vf[ks][nd] = *(const bf16x8*)(Vc + frag_off[ks][nd]);
    }
    __builtin_amdgcn_s_setprio(1);
#pragma unroll
    for (int mt = 0; mt < 2; ++mt)
#pragma unroll
      for (int nd = 0; nd < 4; ++nd)
#pragma unroll
        for (int ks = 0; ks < 2; ++ks)
          accO[mt][nd] = mfma_bf16(pa[mt][ks], vf[ks][nd], accO[mt][nd]);
    __builtin_amdgcn_s_setprio(0);
  };

  stageKV(0, 0);
  __syncthreads();
  for (int kt = 0; kt < 17; ++kt) {
    const int cur = kt & 1;
    if (kt < 16) stageKV(kt + 1, cur ^ 1); // async; flies under compute
    step(kt, cur, kt == 16);
    __syncthreads(); // staging for kt+1 complete; buf[cur] reusable
  }

  // epilogue: one 4-shfl reduce of the deferred l-sum, then store
  const int b = bh / 12, h = bh - (bh / 12) * 12;
#pragma unroll
  for (int mt = 0; mt < 2; ++mt)
#pragma unroll
    for (int j = 0; j < 4; ++j) {
      float sum = lpart[mt][j];
#pragma unroll
      for (int off2 = 1; off2 < 16; off2 <<= 1) sum += __shfl_xor(sum, off2);
      const int t = qb + mt * 16 + q4 * 4 + j;
      if (t > NTOK - 1) continue;
      const float inv = 1.0f / sum;
      const size_t ro = ((size_t)(b * NTOK + t)) * 768 + h * 64;
#pragma unroll
      for (int nd = 0; nd < 4; ++nd) {
        const int d = nd * 16 + l15;
        ao[ro + d] = __float2bfloat16(accO[mt][nd][j] * inv);
      }
    }
}

extern "C" void kernel_launch(void* const* d_in, const int* in_sizes, int n_in,
                              void* d_out, int out_size, void* d_ws, size_t ws_size,
                              hipStream_t stream) {
  const float* x = (const float*)d_in[0];
  const float* sinp = (const float*)d_in[1];
  const float* cosp = (const float*)d_in[2];
  const float* qkvw = (const float*)d_in[3];
  const float* qkvb = (const float*)d_in[4];
  const float* projw = (const float*)d_in[5];
  const float* projb = (const float*)d_in[6];

  char* ws = (char*)d_ws;
  __hip_bfloat16* xhi = (__hip_bfloat16*)(ws + OFF_XHI);
  __hip_bfloat16* wqhi = (__hip_bfloat16*)(ws + OFF_WQHI);
  __hip_bfloat16* pwhi = (__hip_bfloat16*)(ws + OFF_PWHI);
  __hip_bfloat16* pwlo = (__hip_bfloat16*)(ws + OFF_PWLO);
  __hip_bfloat16* qb = (__hip_bfloat16*)(ws + OFF_Q);
  __hip_bfloat16* kb = (__hip_bfloat16*)(ws + OFF_K);
  __hip_bfloat16* vt = (__hip_bfloat16*)(ws + OFF_VT);
  __hip_bfloat16* ao = (__hip_bfloat16*)(ws + OFF_AO);

  // K0: converts (x: plain bf16 cast with zero tail; qkv_w hi; proj_w hi+lo)
  {
    int n_src = M * KDIM, n_dst = MP * KDIM;
    k_tobf16<<<(n_dst + 255) / 256, 256, 0, stream>>>(x, xhi, n_src, n_dst);
    int nw = NQKV * KDIM;
    k_tobf16<<<(nw + 255) / 256, 256, 0, stream>>>(qkvw, wqhi, nw, nw);
    int np = KDIM * KDIM;
    k_split<<<(np + 255) / 256, 256, 0, stream>>>(projw, pwhi, pwlo, np, np);
    int nz = 96 * 64 * (NKVPAD - NTOK);
    k_zero_vt<<<(nz + 255) / 256, 256, 0, stream>>>(vt);
  }
  // K1: QKV GEMM (single term) + bias + RoPE -> q, k(scaled), vT
  // grid 1170 = 18 cols x 65 row-panels, XCD-chunk remapped in-kernel
  k_gemm<0, 2, 18><<<dim3(18 * 65), 256, 0, stream>>>(
      xhi, xhi, wqhi, qkvb, sinp, cosp, qb, kb, vt, nullptr);
  // K2: flash attention -> attn_out bf16 (864 = 8 XCD * 12 heads * 9 qblocks)
  k_attn<<<dim3(864), 256, 0, stream>>>(qb, kb, vt, ao);
  // K3: proj GEMM (attn_out single, w split) + bias -> fp32 out
  // grid 390 = 6 cols x 65 row-panels, XCD-chunk remapped in-kernel
  k_gemm<1, 3, 6><<<dim3(6 * 65), 256, 0, stream>>>(
      ao, pwlo, pwhi, projb, nullptr, nullptr, nullptr, nullptr, nullptr,
      (float*)d_out);
}

// Round 12
// 223.032 us; speedup vs baseline: 1.3151x; 1.0080x over previous
//
#include <hip/hip_runtime.h>
#include <hip/hip_bf16.h>

// ===== Problem constants =====
// B=8, N=1025, C=768, H=12, HD=64
constexpr int NTOK   = 1025;
constexpr int M      = 8 * NTOK;      // 8200 tokens
constexpr int MP     = 8320;          // 65 * 128 padded rows
constexpr int KDIM   = 768;
constexpr int NQKV   = 2304;
constexpr int NKVPAD = 1088;          // 17*64 padded kv length for vT
constexpr float SCALEL2 = 0.125f * 1.44269504f; // 64^-0.5 * log2(e), folded into K

using bf16x8 = __attribute__((ext_vector_type(8))) short;
using f32x4  = __attribute__((ext_vector_type(4))) float;

__device__ __forceinline__ f32x4 mfma_bf16(bf16x8 a, bf16x8 b, f32x4 c) {
  return __builtin_amdgcn_mfma_f32_16x16x32_bf16(a, b, c, 0, 0, 0);
}

__device__ __forceinline__ void gl16(const void* g, void* l) {
  __builtin_amdgcn_global_load_lds(
      (const __attribute__((address_space(1))) void*)g,
      (__attribute__((address_space(3))) void*)l, 16, 0, 0);
}

// counted vmcnt wait (T4): never drain to 0 in the main loop — tile t+1's
// global_load_lds ops stay in flight across the barrier. "memory" clobber
// fences compiler motion of the gl16 intrinsics across the wait.
template <int N> __device__ __forceinline__ void wait_vmcnt() {
  if constexpr (N == 0)
    asm volatile("s_waitcnt vmcnt(0)" ::: "memory");
  else if constexpr (N == 4)
    asm volatile("s_waitcnt vmcnt(4)" ::: "memory");
  else if constexpr (N == 6)
    asm volatile("s_waitcnt vmcnt(6)" ::: "memory");
}

// raw 2^x (args bounded by defer-max <= 8; -1e30 masks flush to 0)
__device__ __forceinline__ float exp2_raw(float x) {
  float r;
  asm("v_exp_f32 %0, %1" : "=v"(r) : "v"(x));
  return r;
}
// hardware-RNE f32->bf16 (1 op vs ~5-op software RNE)
__device__ __forceinline__ __hip_bfloat16 cvt_bf16_raw(float x) {
  unsigned u;
  asm("v_cvt_pk_bf16_f32 %0, %1, %2" : "=v"(u) : "v"(x), "v"(x));
  union { unsigned short s; __hip_bfloat16 b; } c;
  c.s = (unsigned short)(u & 0xffffu);
  return c.b;
}

// ===== Workspace layout (bytes), all 256-aligned =====
constexpr size_t SZ_X     = (size_t)MP * KDIM * 2;        // 12,779,520
constexpr size_t SZ_WQ    = (size_t)NQKV * KDIM * 2;      // 3,538,944
constexpr size_t SZ_PW    = (size_t)KDIM * KDIM * 2;      // 1,179,648
constexpr size_t SZ_QK    = (size_t)96 * NTOK * 64 * 2;   // 12,595,200
constexpr size_t SZ_VT    = (size_t)96 * 64 * NKVPAD * 2; // 13,369,344
constexpr size_t OFF_XHI  = 0;
constexpr size_t OFF_XLO  = OFF_XHI + SZ_X;   // unused since R10 (1-term QKV)
constexpr size_t OFF_WQHI = OFF_XLO + SZ_X;
constexpr size_t OFF_PWHI = OFF_WQHI + SZ_WQ;
constexpr size_t OFF_PWLO = OFF_PWHI + SZ_PW;
constexpr size_t OFF_Q    = OFF_PWLO + SZ_PW;
constexpr size_t OFF_K    = OFF_Q + SZ_QK;
constexpr size_t OFF_VT   = OFF_K + SZ_QK;
constexpr size_t OFF_AO   = OFF_VT + SZ_VT;
// total ~83 MB

// ===== K0a: fp32 -> (hi,lo) bf16 split =====
__global__ void k_split(const float* __restrict__ src, __hip_bfloat16* __restrict__ hi,
                        __hip_bfloat16* __restrict__ lo, int n_src, int n_dst) {
  int i = blockIdx.x * 256 + threadIdx.x;
  if (i >= n_dst) return;
  float v = (i < n_src) ? src[i] : 0.0f;
  __hip_bfloat16 h = __float2bfloat16(v);
  hi[i] = h;
  lo[i] = __float2bfloat16(v - __bfloat162float(h));
}

// K0b: fp32 -> bf16 with zero tail
__global__ void k_tobf16(const float* __restrict__ src, __hip_bfloat16* __restrict__ dst,
                         int n_src, int n_dst) {
  int i = blockIdx.x * 256 + threadIdx.x;
  if (i >= n_dst) return;
  dst[i] = __float2bfloat16((i < n_src) ? src[i] : 0.0f);
}

// zero vT pad columns (keys 1025..1087) so PV MFMA never sees NaN garbage
__global__ void k_zero_vt(__hip_bfloat16* __restrict__ vt) {
  int i = blockIdx.x * 256 + threadIdx.x;
  constexpr int NPADC = NKVPAD - NTOK; // 63
  if (i >= 96 * 64 * NPADC) return;
  int r = i / NPADC;
  int c = NTOK + (i - r * NPADC);
  vt[(size_t)r * NKVPAD + c] = __float2bfloat16(0.0f);
}

// ===== GEMM core: 128x128 tile, BK=32, swizzled LDS =====
// NT=2: single term acc = A*B (QKV). NT=3: acc = A*Bh + A*Bl (proj w-split).
// 1D grid + bijective XCD-chunk remap (T1/m204).
// COUNTED-VMCNT PIPELINE (T4): 3 LDS buffers, depth-2 prefetch; per step
// {wait vmcnt(2*NT) -> tile t complete, t+1 in flight; raw s_barrier;
//  stage(t+2); compute(t)}. Loads are never drained to 0 in the loop.
// Hazards: buffer WAR safe (one barrier/step + 3 bufs); cross-wave LDS
// visibility via each wave's own vmcnt before its barrier; vmcnt in-order.
// LDS chunk-XOR swizzle -> conflict-free ds_read_b128 with linear gl16 dest.
// EPI=0: QKV -> bias + RoPE -> q,k ([bh][t][d] bf16; K pre-scaled by SCALEL2)
//        and vT ([bh][d][t_pad] bf16)
// EPI=1: proj -> bias -> fp32 d_out
template <int EPI, int NT, int NBX>
__global__ __launch_bounds__(256) void k_gemm(
    const __hip_bfloat16* __restrict__ Ahi, const __hip_bfloat16* __restrict__ Asec,
    const __hip_bfloat16* __restrict__ Bhi, const float* __restrict__ bias,
    const float* __restrict__ sinp, const float* __restrict__ cosp,
    __hip_bfloat16* __restrict__ o_q, __hip_bfloat16* __restrict__ o_k,
    __hip_bfloat16* __restrict__ o_vt, float* __restrict__ o_f32) {
  const int tid = threadIdx.x;
  const int w = tid >> 6, lane = tid & 63;
  const int wm = w >> 1, wn = w & 1;
  const int l15 = lane & 15, q4 = lane >> 4;

  // bijective XCD-chunk remap (nwg may not divide by 8)
  const int nwg = gridDim.x;
  const int orig = blockIdx.x;
  const int qc = nwg >> 3, rc = nwg & 7;
  const int xcd = orig & 7, o8 = orig >> 3;
  const int wg =
      (xcd < rc ? xcd * (qc + 1) : rc * (qc + 1) + (xcd - rc) * qc) + o8;
  const int bx = wg % NBX, by = wg / NBX;
  const int mBase = by * 128, nBase = bx * 128;

  __shared__ __hip_bfloat16 sm[3][NT * 4096]; // 3 bufs x NT [128][32] tiles
  constexpr int OFFB = (NT - 1) * 8192;       // byte offset of B_hi tile

  const char* p0 = (const char*)Ahi + (size_t)mBase * (KDIM * 2);
  const char* p1 = (const char*)Asec + (size_t)nBase * (KDIM * 2); // NT==3 only
  const char* p2 = (const char*)Bhi + (size_t)nBase * (KDIM * 2);

  const int slog = ((tid & 3) ^ ((tid >> 3) & 3)) << 4; // staged slot byte offset
  const int ph = ((q4 ^ ((l15 >> 1) & 3)) << 4);        // fragment slot byte offset

  auto stage = [&](int kt, int buf) {
    const int kofs = kt * 64; // bytes into each row
    char* base = (char*)sm[buf];
#pragma unroll
    for (int i = 0; i < 2; ++i) {
      const int c = i * 256 + tid; // 16B chunk index, 512 per tile
      const size_t rb = (size_t)(i * 64 + (tid >> 2)) * (KDIM * 2) + slog + kofs;
      gl16(p0 + rb, base + (size_t)c * 16);
      if (NT == 3) gl16(p1 + rb, base + 8192 + (size_t)c * 16);
      gl16(p2 + rb, base + OFFB + (size_t)c * 16);
    }
  };

  f32x4 acc[4][4] = {};

  stage(0, 0);
  stage(1, 1); // depth-2 prologue: 2*(2*NT) loads in flight

  constexpr int NKT = KDIM / 32; // 24
  for (int kt = 0; kt < NKT; ++kt) {
    if (kt < NKT - 1)
      wait_vmcnt<2 * NT>(); // tile kt landed; kt+1 stays in flight
    else
      wait_vmcnt<0>();
    __builtin_amdgcn_s_barrier(); // all waves' tile-kt data visible in LDS
    if (kt + 2 < NKT) stage(kt + 2, (kt + 2) % 3);
    char* s0 = (char*)sm[kt % 3];
    char* s1 = s0 + 8192;
    char* s2 = s0 + OFFB;
    bf16x8 a0[4], b0[4], b1[4];
#pragma unroll
    for (int mt = 0; mt < 4; ++mt) {
      const int r = wm * 64 + mt * 16 + l15;
      a0[mt] = *(const bf16x8*)(s0 + r * 64 + ph);
    }
#pragma unroll
    for (int nt = 0; nt < 4; ++nt) {
      const int r = wn * 64 + nt * 16 + l15;
      b0[nt] = *(const bf16x8*)(s2 + r * 64 + ph);
      if (NT == 3) b1[nt] = *(const bf16x8*)(s1 + r * 64 + ph);
    }
    __builtin_amdgcn_s_setprio(1);
#pragma unroll
    for (int mt = 0; mt < 4; ++mt)
#pragma unroll
      for (int nt = 0; nt < 4; ++nt) {
        acc[mt][nt] = mfma_bf16(a0[mt], b0[nt], acc[mt][nt]);
        if (NT == 3) acc[mt][nt] = mfma_bf16(a0[mt], b1[nt], acc[mt][nt]);
      }
    __builtin_amdgcn_s_setprio(0);
  }

  // epilogue; C layout: col = lane&15, row = 4*(lane>>4)+j
#pragma unroll
  for (int mt = 0; mt < 4; ++mt)
#pragma unroll
    for (int j = 0; j < 4; ++j) {
      const int gm = mBase + wm * 64 + mt * 16 + q4 * 4 + j;
      if (gm >= M) continue;
      if (EPI == 0) {
        const int b = gm / NTOK;
        const int t = gm - b * NTOK;
#pragma unroll
        for (int nt = 0; nt < 4; ++nt) {
          const int gc = nBase + wn * 64 + nt * 16 + l15;
          float v = acc[mt][nt][j] + bias[gc];
          const int three = gc / 768;
          const int hd = gc - three * 768;
          const int h = hd >> 6, d = hd & 63;
          const int bh = b * 12 + h;
          if (three == 2) {
            o_vt[((size_t)bh * 64 + d) * NKVPAD + t] = __float2bfloat16(v);
          } else {
            if (t > 0) {
              const float pv = acc[mt][nt ^ 2][j] + bias[gc ^ 32];
              const int so = (t - 1) * 64 + d;
              v = v * cosp[so] + ((d < 32) ? -pv : pv) * sinp[so];
            }
            if (three == 0)
              o_q[((size_t)bh * NTOK + t) * 64 + d] = __float2bfloat16(v);
            else  // K: fold softmax scale * log2(e) here (bf16 rel-err scale-invariant)
              o_k[((size_t)bh * NTOK + t) * 64 + d] = __float2bfloat16(v * SCALEL2);
          }
        }
      } else {
#pragma unroll
        for (int nt = 0; nt < 4; ++nt) {
          const int gc = nBase + wn * 64 + nt * 16 + l15;
          o_f32[(size_t)gm * 768 + gc] = acc[mt][nt][j] + bias[gc];
        }
      }
    }
}

// ===== K2: flash attention, 4 waves x 32 q-rows, KV tiles of 64 =====
// Grid: 864 = 8 XCD chunks * 12 heads * 9 q-blocks. K/V staged in LDS once
// per BLOCK via gl16, chunk-XOR swizzled. COUNTED-VMCNT PIPELINE (T4):
// 3 K/V buffer pairs, depth-2 prefetch, raw barrier + vmcnt(4) per step
// (never drained in-loop). Softmax: K pre-scaled (log2 domain); shuffle-free
// defer-max; deferred l-sum; masked tail tile kt=16; raw v_exp/cvt_pk ops;
// all swizzled LDS offsets hoisted out of the K-loop.
__global__ __launch_bounds__(256) void k_attn(
    const __hip_bfloat16* __restrict__ Q, const __hip_bfloat16* __restrict__ Kk,
    const __hip_bfloat16* __restrict__ VT, __hip_bfloat16* __restrict__ ao) {
  __shared__ __hip_bfloat16 Kt[3][64 * 64]; // [key-row][d] swizzled, 8KB/buf
  __shared__ __hip_bfloat16 Vt[3][64 * 64]; // [d-row][key] swizzled, 8KB/buf
  __shared__ __hip_bfloat16 Pl[4][32][72];  // per-wave P tile
  const int tid = threadIdx.x, w = tid >> 6, lane = tid & 63;
  const int l15 = lane & 15, q4 = lane >> 4;
  const int id = blockIdx.x;
  const int xcd = id & 7, sub = id >> 3;   // sub 0..107
  const int hh = sub / 9;                  // head-within-xcd 0..11
  const int bh = xcd * 12 + hh;
  const int qb = (sub - hh * 9) * 128 + w * 32;
  const size_t qbase = (size_t)bh * NTOK * 64;
  const char* Kb = (const char*)(Kk + qbase);
  const char* Vb = (const char*)(VT + (size_t)bh * 64 * NKVPAD);

  // ---- hoisted per-lane offsets (constant across the K-loop) ----
  int frag_off[2][4];
#pragma unroll
  for (int f = 0; f < 4; ++f) {
    const int row = f * 16 + l15;
#pragma unroll
    for (int ks = 0; ks < 2; ++ks)
      frag_off[ks][f] = row * 128 + (((ks * 4 + q4) ^ (row & 7)) << 4);
  }
  int stRow[2], sch16[2], stK[2], stV[2], ldsOff[2];
#pragma unroll
  for (int i = 0; i < 2; ++i) {
    const int c = i * 256 + tid;
    const int row = c >> 3;
    stRow[i] = row;
    sch16[i] = ((c & 7) ^ (row & 7)) << 4;
    stK[i] = row * 128 + sch16[i];
    stV[i] = row * (NKVPAD * 2) + sch16[i];
    ldsOff[i] = c * 16;
  }
  int pw_off[2][4], pa_off[2][2];
#pragma unroll
  for (int mt = 0; mt < 2; ++mt) {
#pragma unroll
    for (int j = 0; j < 4; ++j)
      pw_off[mt][j] = ((w * 32 + mt * 16 + q4 * 4 + j) * 72 + l15) * 2;
#pragma unroll
    for (int ks = 0; ks < 2; ++ks)
      pa_off[mt][ks] = ((w * 32 + mt * 16 + l15) * 72 + ks * 32 + q4 * 8) * 2;
  }
  char* Plc = (char*)&Pl[0][0][0];

  // Q fragments (rows clamped; pad rows are discarded at store)
  bf16x8 qa[2][2];
#pragma unroll
  for (int mt = 0; mt < 2; ++mt) {
    int t = qb + mt * 16 + l15;
    if (t > NTOK - 1) t = NTOK - 1;
#pragma unroll
    for (int ks = 0; ks < 2; ++ks)
      qa[mt][ks] = *(const bf16x8*)(Q + qbase + (size_t)t * 64 + ks * 32 + q4 * 8);
  }

  f32x4 accO[2][4] = {};
  float mrun[2][4], lpart[2][4];
#pragma unroll
  for (int mt = 0; mt < 2; ++mt)
#pragma unroll
    for (int j = 0; j < 4; ++j) {
      mrun[mt][j] = -1e30f;
      lpart[mt][j] = 0.0f;
    }

  auto stageKV = [&](int kt, int b) {
    const int kb0 = kt * 64;
#pragma unroll
    for (int i = 0; i < 2; ++i) {
      const char* srcK;
      if (kt == 16) { // tail: clamp key rows (masked in scores)
        const int srow = min(kb0 + stRow[i], NTOK - 1);
        srcK = Kb + (size_t)srow * 128 + sch16[i];
      } else {
        srcK = Kb + (size_t)kb0 * 128 + stK[i];
      }
      gl16(srcK, (char*)&Kt[b][0] + ldsOff[i]);
      gl16(Vb + (size_t)kb0 * 2 + stV[i], (char*)&Vt[b][0] + ldsOff[i]);
    }
  };

  auto step = [&](int kt, int cur, bool last) {
    // S = Q K^T from LDS (swizzled read), already in log2 domain
    f32x4 s[2][4] = {};
    {
      const char* Kc = (const char*)&Kt[cur][0];
      bf16x8 kfr[2][4];
#pragma unroll
      for (int nt = 0; nt < 4; ++nt)
#pragma unroll
        for (int ks = 0; ks < 2; ++ks)
          kfr[ks][nt] = *(const bf16x8*)(Kc + frag_off[ks][nt]);
      __builtin_amdgcn_s_setprio(1);
#pragma unroll
      for (int mt = 0; mt < 2; ++mt)
#pragma unroll
        for (int nt = 0; nt < 4; ++nt)
#pragma unroll
          for (int ks = 0; ks < 2; ++ks)
            s[mt][nt] = mfma_bf16(qa[mt][ks], kfr[ks][nt], s[mt][nt]);
      __builtin_amdgcn_s_setprio(0);
    }
    // mask dead key columns on the masked tail tile
    if (last) {
#pragma unroll
      for (int nt = 0; nt < 4; ++nt)
        if (1024 + nt * 16 + l15 > NTOK - 1) {
#pragma unroll
          for (int mt = 0; mt < 2; ++mt)
#pragma unroll
            for (int j = 0; j < 4; ++j) s[mt][nt][j] = -1e30f;
        }
    }
    // shuffle-free defer-max test: lane-local col max vs mrun+8, __all()
    float smax[2][4];
    bool okl = true;
#pragma unroll
    for (int mt = 0; mt < 2; ++mt)
#pragma unroll
      for (int j = 0; j < 4; ++j) {
        const float a =
            fmaxf(fmaxf(s[mt][0][j], s[mt][1][j]), fmaxf(s[mt][2][j], s[mt][3][j]));
        smax[mt][j] = a;
        okl = okl && (a <= mrun[mt][j] + 8.0f);
      }
    if (!__all((int)okl)) {
      // slow path: true row max via 4-shfl reduce, then rescale state
#pragma unroll
      for (int mt = 0; mt < 2; ++mt)
#pragma unroll
        for (int j = 0; j < 4; ++j) {
          float m0 = smax[mt][j];
#pragma unroll
          for (int off = 1; off < 16; off <<= 1) m0 = fmaxf(m0, __shfl_xor(m0, off));
          const float mnew = fmaxf(mrun[mt][j], m0);
          const float fsc = exp2_raw(mrun[mt][j] - mnew);
          lpart[mt][j] *= fsc;
          mrun[mt][j] = mnew;
#pragma unroll
          for (int nd = 0; nd < 4; ++nd) accO[mt][nd][j] *= fsc;
        }
    }
    // P = exp2(S - m); per-lane partial sums; stage P to LDS for PV transpose
#pragma unroll
    for (int mt = 0; mt < 2; ++mt)
#pragma unroll
      for (int j = 0; j < 4; ++j) {
        float acc = 0.0f;
        char* pw = Plc + pw_off[mt][j];
#pragma unroll
        for (int nt = 0; nt < 4; ++nt) {
          const float p = exp2_raw(s[mt][nt][j] - mrun[mt][j]);
          acc += p;
          *(__hip_bfloat16*)(pw + nt * 32) = cvt_bf16_raw(p);
        }
        lpart[mt][j] += acc;
      }
    // PV; V fragments from swizzled LDS (wave-private Pl ordered by lgkmcnt)
    bf16x8 pa[2][2], vf[2][4];
#pragma unroll
    for (int mt = 0; mt < 2; ++mt)
#pragma unroll
      for (int ks = 0; ks < 2; ++ks)
        pa[mt][ks] = *(const bf16x8*)(Plc + pa_off[mt][ks]);
    {
      const char* Vc = (const char*)&Vt[cur][0];
#pragma unroll
      for (int nd = 0; nd < 4; ++nd)
#pragma unroll
        for (int ks = 0; ks < 2; ++ks)
          vf[ks][nd] = *(const bf16x8*)(Vc + frag_off[ks][nd]);
    }
    __builtin_amdgcn_s_setprio(1);
#pragma unroll
    for (int mt = 0; mt < 2; ++mt)
#pragma unroll
      for (int nd = 0; nd < 4; ++nd)
#pragma unroll
        for (int ks = 0; ks < 2; ++ks)
          accO[mt][nd] = mfma_bf16(pa[mt][ks], vf[ks][nd], accO[mt][nd]);
    __builtin_amdgcn_s_setprio(0);
  };

  // depth-2 prologue, counted-vmcnt loop (4 gl16 per thread per stage)
  stageKV(0, 0);
  stageKV(1, 1);
  for (int kt = 0; kt < 17; ++kt) {
    if (kt < 16)
      wait_vmcnt<4>(); // tile kt landed; kt+1 stays in flight
    else
      wait_vmcnt<0>();
    __builtin_amdgcn_s_barrier();
    if (kt + 2 < 17) stageKV(kt + 2, (kt + 2) % 3);
    step(kt, kt % 3, kt == 16);
  }

  // epilogue: one 4-shfl reduce of the deferred l-sum, then store
  const int b = bh / 12, h = bh - (bh / 12) * 12;
#pragma unroll
  for (int mt = 0; mt < 2; ++mt)
#pragma unroll
    for (int j = 0; j < 4; ++j) {
      float sum = lpart[mt][j];
#pragma unroll
      for (int off2 = 1; off2 < 16; off2 <<= 1) sum += __shfl_xor(sum, off2);
      const int t = qb + mt * 16 + q4 * 4 + j;
      if (t > NTOK - 1) continue;
      const float inv = 1.0f / sum;
      const size_t ro = ((size_t)(b * NTOK + t)) * 768 + h * 64;
#pragma unroll
      for (int nd = 0; nd < 4; ++nd) {
        const int d = nd * 16 + l15;
        ao[ro + d] = __float2bfloat16(accO[mt][nd][j] * inv);
      }
    }
}

extern "C" void kernel_launch(void* const* d_in, const int* in_sizes, int n_in,
                              void* d_out, int out_size, void* d_ws, size_t ws_size,
                              hipStream_t stream) {
  const float* x = (const float*)d_in[0];
  const float* sinp = (const float*)d_in[1];
  const float* cosp = (const float*)d_in[2];
  const float* qkvw = (const float*)d_in[3];
  const float* qkvb = (const float*)d_in[4];
  const float* projw = (const float*)d_in[5];
  const float* projb = (const float*)d_in[6];

  char* ws = (char*)d_ws;
  __hip_bfloat16* xhi = (__hip_bfloat16*)(ws + OFF_XHI);
  __hip_bfloat16* wqhi = (__hip_bfloat16*)(ws + OFF_WQHI);
  __hip_bfloat16* pwhi = (__hip_bfloat16*)(ws + OFF_PWHI);
  __hip_bfloat16* pwlo = (__hip_bfloat16*)(ws + OFF_PWLO);
  __hip_bfloat16* qb = (__hip_bfloat16*)(ws + OFF_Q);
  __hip_bfloat16* kb = (__hip_bfloat16*)(ws + OFF_K);
  __hip_bfloat16* vt = (__hip_bfloat16*)(ws + OFF_VT);
  __hip_bfloat16* ao = (__hip_bfloat16*)(ws + OFF_AO);

  // K0: converts (x: plain bf16 cast with zero tail; qkv_w hi; proj_w hi+lo)
  {
    int n_src = M * KDIM, n_dst = MP * KDIM;
    k_tobf16<<<(n_dst + 255) / 256, 256, 0, stream>>>(x, xhi, n_src, n_dst);
    int nw = NQKV * KDIM;
    k_tobf16<<<(nw + 255) / 256, 256, 0, stream>>>(qkvw, wqhi, nw, nw);
    int np = KDIM * KDIM;
    k_split<<<(np + 255) / 256, 256, 0, stream>>>(projw, pwhi, pwlo, np, np);
    int nz = 96 * 64 * (NKVPAD - NTOK);
    k_zero_vt<<<(nz + 255) / 256, 256, 0, stream>>>(vt);
  }
  // K1: QKV GEMM (single term) + bias + RoPE -> q, k(scaled), vT
  // grid 1170 = 18 cols x 65 row-panels, XCD-chunk remapped in-kernel
  k_gemm<0, 2, 18><<<dim3(18 * 65), 256, 0, stream>>>(
      xhi, xhi, wqhi, qkvb, sinp, cosp, qb, kb, vt, nullptr);
  // K2: flash attention -> attn_out bf16 (864 = 8 XCD * 12 heads * 9 qblocks)
  k_attn<<<dim3(864), 256, 0, stream>>>(qb, kb, vt, ao);
  // K3: proj GEMM (attn_out single, w split) + bias -> fp32 out
  // grid 390 = 6 cols x 65 row-panels, XCD-chunk remapped in-kernel
  k_gemm<1, 3, 6><<<dim3(6 * 65), 256, 0, stream>>>(
      ao, pwlo, pwhi, projb, nullptr, nullptr, nullptr, nullptr, nullptr,
      (float*)d_out);
}